// Round 15
// baseline (406.437 us; speedup 1.0000x reference)
//
#include <hip/hip_runtime.h>
#include <math.h>

#define THREADS 256

// ---- v10 parameters ----
#define SH 7                 // col-bin width 128
#define BINW 128
#define MAXBIN4 2048         // NBIN cap (N <= 262144)
#define SHR4 10              // row-group width 1024
#define GWR4 1024
#define MAXGR4 256
#define SCHUNK 16384         // edges per binning block
#define GCAP 10240           // gather LDS bucket capacity (40KB; max bucket ~8.5K)
#define FP8S 64.0f
#define FP8SI (1.0f / 64.0f)

typedef float v2f __attribute__((ext_vector_type(2)));

// bf16 helpers (RNE)
__device__ inline unsigned short f2bf(float f) {
    unsigned int u = __float_as_uint(f);
    return (unsigned short)((u + 0x7FFFu + ((u >> 16) & 1u)) >> 16);
}
__device__ inline float bfLo(unsigned int u) { return __uint_as_float(u << 16); }
__device__ inline float bfHi(unsigned int u) { return __uint_as_float(u & 0xFFFF0000u); }

// fp8 e4m3 helpers (HW cvt, gfx950)
__device__ inline unsigned int pk4_fp8(float a, float b, float c, float d) {
    int u = __builtin_amdgcn_cvt_pk_fp8_f32(a, b, 0, false);
    u = __builtin_amdgcn_cvt_pk_fp8_f32(c, d, u, true);
    return (unsigned int)u;
}

// ======================= scans =======================

__device__ inline void scan_one_col(int* D, int* binTot, int NBLK, int NBIN, int b) {
    __shared__ int tmp[THREADS];
    int carry = 0;
    for (int base = 0; base < NBLK; base += THREADS) {
        int idx = base + threadIdx.x;
        int v = (idx < NBLK) ? D[(size_t)idx * NBIN + b] : 0;
        tmp[threadIdx.x] = v;
        __syncthreads();
        for (int d = 1; d < THREADS; d <<= 1) {
            int u = (threadIdx.x >= d) ? tmp[threadIdx.x - d] : 0;
            __syncthreads();
            tmp[threadIdx.x] += u;
            __syncthreads();
        }
        if (idx < NBLK) D[(size_t)idx * NBIN + b] = carry + tmp[threadIdx.x] - v;
        carry += tmp[THREADS - 1];
        __syncthreads();
    }
    if (threadIdx.x == 0) binTot[b] = carry;
}

__global__ void scan_col2_kernel(int* __restrict__ Dc, int* __restrict__ totC, int NBINc,
                                 int* __restrict__ Dr, int* __restrict__ totR, int NBINr,
                                 int NBLK) {
    int b = blockIdx.x;
    if (b < NBINc) scan_one_col(Dc, totC, NBLK, NBINc, b);
    else           scan_one_col(Dr, totR, NBLK, NBINr, b - NBINc);
}

__device__ inline void scan_bins_one(const int* binTot, int* binBase, int NBIN) {
    __shared__ int tmp[1024];
    int carry = 0;
    for (int base = 0; base < NBIN; base += 1024) {
        int i = base + threadIdx.x;
        int v = (i < NBIN) ? binTot[i] : 0;
        tmp[threadIdx.x] = v;
        __syncthreads();
        for (int d = 1; d < 1024; d <<= 1) {
            int u = (threadIdx.x >= d) ? tmp[threadIdx.x - d] : 0;
            __syncthreads();
            tmp[threadIdx.x] += u;
            __syncthreads();
        }
        if (i < NBIN) binBase[i] = carry + tmp[threadIdx.x] - v;
        carry += tmp[1023];
        __syncthreads();
    }
    if (threadIdx.x == 0) binBase[NBIN] = carry;
}

__global__ void scan_bins2_kernel(const int* __restrict__ totC, int* __restrict__ basC, int NBINc,
                                  const int* __restrict__ totR, int* __restrict__ basR, int NBINr) {
    if (blockIdx.x == 0) scan_bins_one(totC, basC, NBINc);
    else                 scan_bins_one(totR, basR, NBINr);
}

// ======================= v10 build =======================

__global__ __launch_bounds__(512) void hist4_kernel(const int* __restrict__ row,
                                                    const int* __restrict__ col,
                                                    int* __restrict__ D2c, int* __restrict__ D2r,
                                                    int E, int NBIN, int NGR) {
    __shared__ int hc[MAXBIN4], hr[MAXGR4];
    int t = threadIdx.x;
    for (int i = t; i < NBIN; i += 512) hc[i] = 0;
    for (int i = t; i < NGR; i += 512) hr[i] = 0;
    __syncthreads();
    int base = blockIdx.x * SCHUNK;
    int lim = min(SCHUNK, E - base);
    for (int k = t; k < lim; k += 512) {
        int e = base + k;
        atomicAdd(&hc[col[e] >> SH], 1);
        atomicAdd(&hr[row[e] >> SHR4], 1);
    }
    __syncthreads();
    for (int i = t; i < NBIN; i += 512) D2c[(size_t)blockIdx.x * NBIN + i] = hc[i];
    for (int i = t; i < NGR; i += 512) D2r[(size_t)blockIdx.x * NGR + i] = hr[i];
}

// col scatter: counts derived from scanned D2c deltas
__global__ __launch_bounds__(512) void scatter_colS(const int* __restrict__ row,
                                                    const int* __restrict__ col,
                                                    const int* __restrict__ D2c,
                                                    const int* __restrict__ totC,
                                                    const int* __restrict__ basC,
                                                    unsigned int* __restrict__ A1,
                                                    int E, int NBIN, int NBLK) {
    __shared__ unsigned int buf[SCHUNK];        // 64KB
    __shared__ int ls[MAXBIN4];                 // 8KB (starts -> ends)
    __shared__ unsigned short secbin[SCHUNK / 32];  // 1KB
    __shared__ int tmps[512];
    __shared__ int carry;
    int t = threadIdx.x;
    int base = blockIdx.x * SCHUNK;
    int lim = min(SCHUNK, E - base);
    const int* Dg  = D2c + (size_t)blockIdx.x * NBIN;
    const int* Dn  = (blockIdx.x == NBLK - 1) ? totC : Dg + NBIN;
    if (t == 0) carry = 0;
    __syncthreads();
    for (int cb = 0; cb < NBIN; cb += 512) {
        int idx = cb + t;
        int v = (idx < NBIN) ? (Dn[idx] - Dg[idx]) : 0;
        tmps[t] = v;
        __syncthreads();
        for (int d = 1; d < 512; d <<= 1) {
            int u = (t >= d) ? tmps[t - d] : 0;
            __syncthreads();
            tmps[t] += u;
            __syncthreads();
        }
        if (idx < NBIN) ls[idx] = carry + tmps[t] - v;
        __syncthreads();
        if (t == 0) carry += tmps[511];
        __syncthreads();
    }
    for (int k = t; k < lim; k += 512) {
        int e = base + k;
        int c = col[e], r = row[e];
        int bin = c >> SH;
        int p = atomicAdd(&ls[bin], 1);
        buf[p] = (unsigned int)r | ((unsigned int)(c & (BINW - 1)) << 18);
    }
    __syncthreads();
    {
        int pos = t * 32;
        if (pos < lim) {
            int lo = 0, hi = NBIN;
            while (lo < hi) { int mid = (lo + hi) >> 1; if (ls[mid] > pos) hi = mid; else lo = mid + 1; }
            secbin[t] = (unsigned short)lo;
        }
    }
    __syncthreads();
    for (int i = t; i < lim; i += 512) {
        int bin = secbin[i >> 5];
        while (ls[bin] <= i) ++bin;
        int start = (bin > 0) ? ls[bin - 1] : 0;
        A1[Dg[bin] + basC[bin] + (i - start)] = buf[i];
    }
}

// row scatter: counts from D2r deltas
__global__ __launch_bounds__(512) void scatter_rowS(const int* __restrict__ row,
                                                    const int* __restrict__ D2r,
                                                    const int* __restrict__ totR,
                                                    const int* __restrict__ basR,
                                                    unsigned short* __restrict__ B1,
                                                    int E, int NGR, int NBLK) {
    __shared__ unsigned short buf16[SCHUNK];   // 32KB
    __shared__ unsigned char gof[SCHUNK];      // 16KB
    __shared__ int cnt[MAXGR4], ls[MAXGR4], ob[MAXGR4];
    __shared__ int tmps[512];
    int t = threadIdx.x;
    int base = blockIdx.x * SCHUNK;
    int lim = min(SCHUNK, E - base);
    const int* Dg = D2r + (size_t)blockIdx.x * NGR;
    const int* Dn = (blockIdx.x == NBLK - 1) ? totR : Dg + NGR;
    int myv = 0;
    if (t < NGR) {
        int cur = Dg[t];
        myv = Dn[t] - cur;
        ob[t] = cur + basR[t];
        cnt[t] = 0;
    }
    tmps[t] = myv;
    __syncthreads();
    for (int d = 1; d < 512; d <<= 1) {
        int u = (t >= d) ? tmps[t - d] : 0;
        __syncthreads();
        tmps[t] += u;
        __syncthreads();
    }
    if (t < NGR) ls[t] = tmps[t] - myv;
    __syncthreads();
    for (int k = t; k < lim; k += 512) {
        int r = row[base + k];
        int g = r >> SHR4;
        int p = ls[g] + atomicAdd(&cnt[g], 1);
        buf16[p] = (unsigned short)(r & (GWR4 - 1));
        gof[p] = (unsigned char)g;
    }
    __syncthreads();
    for (int i = t; i < lim; i += 512) {
        int g = gof[i];
        B1[ob[g] + (i - ls[g])] = buf16[i];
    }
}

// per row-group out-degree histogram -> dis, fused xs_bf = bf16(dis*x)
__global__ void deg4_kernel(const unsigned short* __restrict__ B1,
                            const int* __restrict__ basR,
                            const float* __restrict__ x,
                            float* __restrict__ dis, uint4* __restrict__ xsb, int N) {
    __shared__ int cnt[GWR4];
    int b = blockIdx.x;
    for (int i = threadIdx.x; i < GWR4; i += blockDim.x) cnt[i] = 0;
    __syncthreads();
    int p0 = basR[b], p1 = basR[b + 1];
    for (int i = p0 + threadIdx.x; i < p1; i += blockDim.x)
        atomicAdd(&cnt[B1[i]], 1);
    __syncthreads();
    for (int i = threadIdx.x; i < GWR4; i += blockDim.x) {
        int node = (b << SHR4) + i;
        if (node < N) {
            int c = cnt[i];
            float d = c > 0 ? rsqrtf((float)c) : 0.f;
            dis[node] = d;
            const float4* xr = reinterpret_cast<const float4*>(x + (size_t)node * 8);
            float4 a = xr[0], bb = xr[1];
            uint4 o;
            o.x = (unsigned int)f2bf(d * a.x) | ((unsigned int)f2bf(d * a.y) << 16);
            o.y = (unsigned int)f2bf(d * a.z) | ((unsigned int)f2bf(d * a.w) << 16);
            o.z = (unsigned int)f2bf(d * bb.x) | ((unsigned int)f2bf(d * bb.y) << 16);
            o.w = (unsigned int)f2bf(d * bb.z) | ((unsigned int)f2bf(d * bb.w) << 16);
            xsb[node] = o;
        }
    }
}

// ======================= v10 fused sort+gather+dense (1024-thread, 8 lanes/node) ===========

__global__ __launch_bounds__(1024) void gather1S(unsigned int* __restrict__ A1,
                                                 const int* __restrict__ basC,
                                                 const uint4* __restrict__ xsb,
                                                 const float* __restrict__ x,
                                                 const float* __restrict__ dis,
                                                 const float* __restrict__ W0,
                                                 const float* __restrict__ W1,
                                                 const float* __restrict__ b1,
                                                 const float* __restrict__ W20,
                                                 const float* __restrict__ b2,
                                                 unsigned int* __restrict__ h1s8,
                                                 float* __restrict__ P0,
                                                 int* __restrict__ off, int N) {
    __shared__ unsigned int lsrc[GCAP];             // 40KB
    __shared__ int cnt[BINW], fill[BINW], ls[BINW + 1], tmp2[BINW];
    __shared__ float sW0[128], sW1[128], sb1[16], sW20[256], sb2[16];
    int t = threadIdx.x, b = blockIdx.x;
    for (int i = t; i < 128; i += 1024) { sW0[i] = W0[i]; sW1[i] = W1[i]; }
    for (int i = t; i < 256; i += 1024) sW20[i] = W20[i];
    if (t < 16) { sb1[t] = b1[t]; sb2[t] = b2[t]; }
    if (t < BINW) { cnt[t] = 0; fill[t] = 0; }
    __syncthreads();
    int p0 = basC[b], p1 = basC[b + 1], sz = p1 - p0;

    if (sz <= GCAP) {
        for (int i = t; i < sz; i += 1024)
            atomicAdd(&cnt[(A1[p0 + i] >> 18) & (BINW - 1)], 1);
        __syncthreads();
        {
            int v = (t < BINW) ? cnt[t] : 0;
            if (t < BINW) tmp2[t] = v;
            __syncthreads();
            for (int d = 1; d < BINW; d <<= 1) {
                int u = (t >= d && t < BINW) ? tmp2[t - d] : 0;
                __syncthreads();
                if (t < BINW) tmp2[t] += u;
                __syncthreads();
            }
            if (t < BINW) ls[t] = tmp2[t] - v;
            if (t == BINW - 1) ls[BINW] = tmp2[BINW - 1];
        }
        __syncthreads();
        for (int i = t; i < sz; i += 1024) {
            unsigned int a = A1[p0 + i];
            int cl = (a >> 18) & (BINW - 1);
            lsrc[ls[cl] + atomicAdd(&fill[cl], 1)] = a;
        }
        __syncthreads();
        for (int i = t; i < sz; i += 1024) A1[p0 + i] = lsrc[i];
        if (t < BINW) {
            int node = (b << SH) + t;
            if (node < N) off[node] = p0 + ls[t];
        }
        int n = t >> 3, sub = t & 7;
        int node = (b << SH) + n;
        if (node < N) {
            float tx[8] = {0, 0, 0, 0, 0, 0, 0, 0};
            for (int k = ls[n] + sub; k < ls[n + 1]; k += 8) {
                int r = (int)(lsrc[k] & 0x3FFFFu);
                uint4 q = xsb[r];
                tx[0] += bfLo(q.x); tx[1] += bfHi(q.x);
                tx[2] += bfLo(q.y); tx[3] += bfHi(q.y);
                tx[4] += bfLo(q.z); tx[5] += bfHi(q.z);
                tx[6] += bfLo(q.w); tx[7] += bfHi(q.w);
            }
#pragma unroll
            for (int i = 0; i < 8; ++i) {
                tx[i] += __shfl_xor(tx[i], 1);
                tx[i] += __shfl_xor(tx[i], 2);
                tx[i] += __shfl_xor(tx[i], 4);
            }
            if (sub < 4) {
                float d = dis[node], sc = -d;
                float xa[8];
                const float4* xr = reinterpret_cast<const float4*>(x + (size_t)node * 8);
                float4 a = xr[0], bb = xr[1];
                xa[0] = a.x; xa[1] = a.y; xa[2] = a.z; xa[3] = a.w;
                xa[4] = bb.x; xa[5] = bb.y; xa[6] = bb.z; xa[7] = bb.w;
                int ob = sub * 4;
                float acc[4];
#pragma unroll
                for (int j = 0; j < 4; ++j) acc[j] = sb1[ob + j];
#pragma unroll
                for (int f = 0; f < 8; ++f) {
                    float xv = xa[f], tv = sc * tx[f];
#pragma unroll
                    for (int j = 0; j < 4; ++j)
                        acc[j] += xv * sW0[f * 16 + ob + j] + tv * sW1[f * 16 + ob + j];
                }
                float h[4];
#pragma unroll
                for (int j = 0; j < 4; ++j) h[j] = fmaxf(acc[j], 0.f);
                float ds = d * FP8S;
                h1s8[(size_t)node * 4 + sub] = pk4_fp8(ds * h[0], ds * h[1], ds * h[2], ds * h[3]);
                float hall[16];
#pragma unroll
                for (int src = 0; src < 4; ++src) {
#pragma unroll
                    for (int j = 0; j < 4; ++j) hall[src * 4 + j] = __shfl(h[j], src, 8);
                }
                float pp[4];
#pragma unroll
                for (int j = 0; j < 4; ++j) pp[j] = sb2[ob + j];
#pragma unroll
                for (int f = 0; f < 16; ++f) {
                    float hv = hall[f];
#pragma unroll
                    for (int j = 0; j < 4; ++j) pp[j] += hv * sW20[f * 16 + ob + j];
                }
                reinterpret_cast<float4*>(P0 + (size_t)node * 16)[sub] =
                    make_float4(pp[0], pp[1], pp[2], pp[3]);
            }
        }
    } else {
        // oversized bin (not expected): LDS f32-atomic accumulation; still writes off[]
        float* txf = (float*)lsrc;   // [BINW][9]
        for (int i = t; i < BINW * 9; i += 1024) txf[i] = 0.f;
        __syncthreads();
        for (int i = t; i < sz; i += 1024) {
            unsigned int a = A1[p0 + i];
            int r = a & 0x3FFFF, cl = (a >> 18) & (BINW - 1);
            atomicAdd(&cnt[cl], 1);
            uint4 q = xsb[r];
            atomicAdd(&txf[cl * 9 + 0], bfLo(q.x)); atomicAdd(&txf[cl * 9 + 1], bfHi(q.x));
            atomicAdd(&txf[cl * 9 + 2], bfLo(q.y)); atomicAdd(&txf[cl * 9 + 3], bfHi(q.y));
            atomicAdd(&txf[cl * 9 + 4], bfLo(q.z)); atomicAdd(&txf[cl * 9 + 5], bfHi(q.z));
            atomicAdd(&txf[cl * 9 + 6], bfLo(q.w)); atomicAdd(&txf[cl * 9 + 7], bfHi(q.w));
        }
        __syncthreads();
        if (t == 0) { int a = 0; for (int i = 0; i < BINW; ++i) { ls[i] = a; a += cnt[i]; } }
        __syncthreads();
        if (t < BINW) {
            int node = (b << SH) + t;
            if (node < N) {
                off[node] = p0 + ls[t];
                float d = dis[node], sc = -d;
                float xa[8];
                const float4* xr = reinterpret_cast<const float4*>(x + (size_t)node * 8);
                float4 a = xr[0], bb = xr[1];
                xa[0] = a.x; xa[1] = a.y; xa[2] = a.z; xa[3] = a.w;
                xa[4] = bb.x; xa[5] = bb.y; xa[6] = bb.z; xa[7] = bb.w;
                float acc[16];
#pragma unroll
                for (int o = 0; o < 16; ++o) acc[o] = sb1[o];
#pragma unroll
                for (int f = 0; f < 8; ++f) {
                    float xv = xa[f], tv = sc * txf[t * 9 + f];
#pragma unroll
                    for (int o = 0; o < 16; ++o)
                        acc[o] += xv * sW0[f * 16 + o] + tv * sW1[f * 16 + o];
                }
                float h[16];
#pragma unroll
                for (int o = 0; o < 16; ++o) h[o] = fmaxf(acc[o], 0.f);
                float ds = d * FP8S;
#pragma unroll
                for (int v = 0; v < 4; ++v)
                    h1s8[(size_t)node * 4 + v] = pk4_fp8(ds * h[v * 4 + 0], ds * h[v * 4 + 1],
                                                         ds * h[v * 4 + 2], ds * h[v * 4 + 3]);
                float pp[16];
#pragma unroll
                for (int o = 0; o < 16; ++o) pp[o] = sb2[o];
#pragma unroll
                for (int f = 0; f < 16; ++f) {
                    float hv = h[f];
#pragma unroll
                    for (int o = 0; o < 16; ++o) pp[o] += hv * sW20[f * 16 + o];
                }
                float4* po = reinterpret_cast<float4*>(P0 + (size_t)node * 16);
#pragma unroll
                for (int v = 0; v < 4; ++v)
                    po[v] = make_float4(pp[v * 4], pp[v * 4 + 1], pp[v * 4 + 2], pp[v * 4 + 3]);
            }
        }
    }
}

__global__ __launch_bounds__(1024) void gather2S(const unsigned int* __restrict__ A1,
                                                 const int* __restrict__ basC,
                                                 const int* __restrict__ off,
                                                 const uint4* __restrict__ h1s8,
                                                 const float* __restrict__ P0,
                                                 const float* __restrict__ dis,
                                                 const float* __restrict__ W21,
                                                 const float* __restrict__ Wr,
                                                 const float* __restrict__ br,
                                                 float* __restrict__ s, int N) {
    __shared__ unsigned int lsrc[GCAP];
    __shared__ float sW1[256], sWr[16], sbr;
    int t = threadIdx.x, b = blockIdx.x;
    for (int i = t; i < 256; i += 1024) sW1[i] = W21[i];
    if (t < 16) sWr[t] = Wr[t];
    if (t == 0) sbr = br[0];
    __syncthreads();
    int p0 = basC[b], p1 = basC[b + 1], sz = p1 - p0;

    if (sz <= GCAP) {
        for (int i = t; i < sz; i += 1024) lsrc[i] = __builtin_nontemporal_load(&A1[p0 + i]);
        __syncthreads();
        int n = t >> 3, sub = t & 7;
        int node = (b << SH) + n;
        if (node < N) {
            int st = off[node] - p0;
            int en = (n == BINW - 1 || node == N - 1) ? sz : off[node + 1] - p0;
            float tx[16];
#pragma unroll
            for (int o = 0; o < 16; ++o) tx[o] = 0.f;
            for (int k = st + sub; k < en; k += 8) {
                int r = (int)(lsrc[k] & 0x3FFFFu);
                uint4 q = h1s8[r];
                v2f p;
                p = __builtin_amdgcn_cvt_pk_f32_fp8((int)q.x, false); tx[0]  += p.x; tx[1]  += p.y;
                p = __builtin_amdgcn_cvt_pk_f32_fp8((int)q.x, true);  tx[2]  += p.x; tx[3]  += p.y;
                p = __builtin_amdgcn_cvt_pk_f32_fp8((int)q.y, false); tx[4]  += p.x; tx[5]  += p.y;
                p = __builtin_amdgcn_cvt_pk_f32_fp8((int)q.y, true);  tx[6]  += p.x; tx[7]  += p.y;
                p = __builtin_amdgcn_cvt_pk_f32_fp8((int)q.z, false); tx[8]  += p.x; tx[9]  += p.y;
                p = __builtin_amdgcn_cvt_pk_f32_fp8((int)q.z, true);  tx[10] += p.x; tx[11] += p.y;
                p = __builtin_amdgcn_cvt_pk_f32_fp8((int)q.w, false); tx[12] += p.x; tx[13] += p.y;
                p = __builtin_amdgcn_cvt_pk_f32_fp8((int)q.w, true);  tx[14] += p.x; tx[15] += p.y;
            }
#pragma unroll
            for (int i = 0; i < 16; ++i) {
                tx[i] += __shfl_xor(tx[i], 1);
                tx[i] += __shfl_xor(tx[i], 2);
                tx[i] += __shfl_xor(tx[i], 4);
            }
            if (sub < 4) {
                float sc = -dis[node] * FP8SI;
                int ob = sub * 4;
                float4 pq = reinterpret_cast<const float4*>(P0 + (size_t)node * 16)[sub];
                float acc[4] = {pq.x, pq.y, pq.z, pq.w};
#pragma unroll
                for (int f = 0; f < 16; ++f) {
                    float tv = sc * tx[f];
#pragma unroll
                    for (int j = 0; j < 4; ++j) acc[j] += tv * sW1[f * 16 + ob + j];
                }
                float sv = 0.f;
#pragma unroll
                for (int j = 0; j < 4; ++j) sv += fmaxf(acc[j], 0.f) * sWr[ob + j];
                sv += __shfl_xor(sv, 1);
                sv += __shfl_xor(sv, 2);
                if (sub == 0) s[node] = sv + sbr;
            }
        }
    } else {
        float* txf = (float*)lsrc;   // [BINW][17]
        for (int i = t; i < BINW * 17; i += 1024) txf[i] = 0.f;
        __syncthreads();
        for (int i = t; i < sz; i += 1024) {
            unsigned int a = A1[p0 + i];
            int r = a & 0x3FFFF, cl = (a >> 18) & (BINW - 1);
            uint4 q = h1s8[r];
            v2f p;
            p = __builtin_amdgcn_cvt_pk_f32_fp8((int)q.x, false);
            atomicAdd(&txf[cl * 17 + 0], p.x);  atomicAdd(&txf[cl * 17 + 1], p.y);
            p = __builtin_amdgcn_cvt_pk_f32_fp8((int)q.x, true);
            atomicAdd(&txf[cl * 17 + 2], p.x);  atomicAdd(&txf[cl * 17 + 3], p.y);
            p = __builtin_amdgcn_cvt_pk_f32_fp8((int)q.y, false);
            atomicAdd(&txf[cl * 17 + 4], p.x);  atomicAdd(&txf[cl * 17 + 5], p.y);
            p = __builtin_amdgcn_cvt_pk_f32_fp8((int)q.y, true);
            atomicAdd(&txf[cl * 17 + 6], p.x);  atomicAdd(&txf[cl * 17 + 7], p.y);
            p = __builtin_amdgcn_cvt_pk_f32_fp8((int)q.z, false);
            atomicAdd(&txf[cl * 17 + 8], p.x);  atomicAdd(&txf[cl * 17 + 9], p.y);
            p = __builtin_amdgcn_cvt_pk_f32_fp8((int)q.z, true);
            atomicAdd(&txf[cl * 17 + 10], p.x); atomicAdd(&txf[cl * 17 + 11], p.y);
            p = __builtin_amdgcn_cvt_pk_f32_fp8((int)q.w, false);
            atomicAdd(&txf[cl * 17 + 12], p.x); atomicAdd(&txf[cl * 17 + 13], p.y);
            p = __builtin_amdgcn_cvt_pk_f32_fp8((int)q.w, true);
            atomicAdd(&txf[cl * 17 + 14], p.x); atomicAdd(&txf[cl * 17 + 15], p.y);
        }
        __syncthreads();
        if (t < BINW) {
            int node = (b << SH) + t;
            if (node < N) {
                float sc = -dis[node] * FP8SI;
                float acc[16];
                const float4* pr = reinterpret_cast<const float4*>(P0 + (size_t)node * 16);
#pragma unroll
                for (int v = 0; v < 4; ++v) {
                    float4 q = pr[v];
                    acc[v * 4 + 0] = q.x; acc[v * 4 + 1] = q.y;
                    acc[v * 4 + 2] = q.z; acc[v * 4 + 3] = q.w;
                }
#pragma unroll
                for (int f = 0; f < 16; ++f) {
                    float tv = sc * txf[t * 17 + f];
#pragma unroll
                    for (int o = 0; o < 16; ++o) acc[o] += tv * sW1[f * 16 + o];
                }
                float sv = sbr;
#pragma unroll
                for (int o = 0; o < 16; ++o) sv += fmaxf(acc[o], 0.f) * sWr[o];
                s[node] = sv;
            }
        }
    }
}

__global__ void softmax_kernel(const float* __restrict__ s, const int* __restrict__ batch,
                               float* __restrict__ out, int N) {
    int g = blockIdx.x;
    __shared__ float red[THREADS];
    int lo, hi;
    { int a = 0, b = N; while (a < b) { int mid = (a + b) >> 1; if (batch[mid] < g) a = mid + 1; else b = mid; } lo = a; }
    { int a = lo, b = N; while (a < b) { int mid = (a + b) >> 1; if (batch[mid] < g + 1) a = mid + 1; else b = mid; } hi = a; }
    float mx = -INFINITY;
    for (int i = lo + threadIdx.x; i < hi; i += THREADS) mx = fmaxf(mx, s[i]);
    red[threadIdx.x] = mx;
    __syncthreads();
    for (int d = THREADS / 2; d > 0; d >>= 1) {
        if (threadIdx.x < d) red[threadIdx.x] = fmaxf(red[threadIdx.x], red[threadIdx.x + d]);
        __syncthreads();
    }
    mx = red[0];
    __syncthreads();
    float sum = 0.f;
    for (int i = lo + threadIdx.x; i < hi; i += THREADS) sum += expf(s[i] - mx);
    red[threadIdx.x] = sum;
    __syncthreads();
    for (int d = THREADS / 2; d > 0; d >>= 1) {
        if (threadIdx.x < d) red[threadIdx.x] += red[threadIdx.x + d];
        __syncthreads();
    }
    float inv = 1.f / red[0];
    for (int i = lo + threadIdx.x; i < hi; i += THREADS) out[i] = expf(s[i] - mx) * inv;
}

// ======================= generic fallback (round-2 CSR + w4 gathers, fp32) =======================

__global__ void deg_cnt_kernel(const int* __restrict__ row, const int* __restrict__ col,
                               int* __restrict__ deg_i, int* __restrict__ cnt, int E) {
    int e = blockIdx.x * blockDim.x + threadIdx.x;
    if (e >= E) return;
    atomicAdd(&deg_i[row[e]], 1);
    atomicAdd(&cnt[col[e]], 1);
}

__global__ void dis_kernel_i(const int* __restrict__ deg_i, float* __restrict__ dis, int N) {
    int i = blockIdx.x * blockDim.x + threadIdx.x;
    if (i < N) {
        int d = deg_i[i];
        dis[i] = d > 0 ? rsqrtf((float)d) : 0.f;
    }
}

__global__ void scan1_kernel(const int* __restrict__ cnt, int* __restrict__ off,
                             int* __restrict__ bsum, int n) {
    __shared__ int tmp[THREADS];
    int i = blockIdx.x * THREADS + threadIdx.x;
    int v = (i < n) ? cnt[i] : 0;
    tmp[threadIdx.x] = v;
    __syncthreads();
    for (int d = 1; d < THREADS; d <<= 1) {
        int t = (threadIdx.x >= d) ? tmp[threadIdx.x - d] : 0;
        __syncthreads();
        tmp[threadIdx.x] += t;
        __syncthreads();
    }
    if (i < n) off[i] = tmp[threadIdx.x] - v;
    if (threadIdx.x == THREADS - 1) bsum[blockIdx.x] = tmp[threadIdx.x];
}

__global__ void scan2_kernel(int* __restrict__ bsum, int nb) {
    __shared__ int tmp[1024];
    int carry = 0;
    for (int base = 0; base < nb; base += 1024) {
        int i = base + threadIdx.x;
        int v = (i < nb) ? bsum[i] : 0;
        tmp[threadIdx.x] = v;
        __syncthreads();
        for (int d = 1; d < 1024; d <<= 1) {
            int t = (threadIdx.x >= d) ? tmp[threadIdx.x - d] : 0;
            __syncthreads();
            tmp[threadIdx.x] += t;
            __syncthreads();
        }
        if (i < nb) bsum[i] = carry + tmp[threadIdx.x] - v;
        carry += tmp[1023];
        __syncthreads();
    }
}

__global__ void scan3_kernel(int* __restrict__ off, const int* __restrict__ bsum, int n) {
    int i = blockIdx.x * THREADS + threadIdx.x;
    if (i < n) off[i] += bsum[blockIdx.x];
}

__global__ void fill_csr_kernel(const int* __restrict__ row, const int* __restrict__ col,
                                const int* __restrict__ off, int* __restrict__ fill,
                                int* __restrict__ csr_src, int E) {
    int e = blockIdx.x * blockDim.x + threadIdx.x;
    if (e >= E) return;
    int c = col[e];
    int p = off[c] + atomicAdd(&fill[c], 1);
    csr_src[p] = row[e];
}

__global__ void gather_dense1_w4(const int* __restrict__ off, const int* __restrict__ csr_src,
                                 const float* __restrict__ dis, const float* __restrict__ x,
                                 const float* __restrict__ W0, const float* __restrict__ W1,
                                 const float* __restrict__ b, float* __restrict__ h1,
                                 int N, int E) {
    __shared__ float sW0[128], sW1[128], sb[16];
    for (int i = threadIdx.x; i < 128; i += blockDim.x) { sW0[i] = W0[i]; sW1[i] = W1[i]; }
    if (threadIdx.x < 16) sb[threadIdx.x] = b[threadIdx.x];
    __syncthreads();
    int t = blockIdx.x * blockDim.x + threadIdx.x;
    int g = t >> 2, sub = t & 3;
    if (g >= N) return;
    int p0 = off[g], p1 = (g == N - 1) ? E : off[g + 1];
    float tx[8] = {0, 0, 0, 0, 0, 0, 0, 0};
    for (int p = p0 + sub; p < p1; p += 4) {
        int src = csr_src[p];
        float wv = dis[src];
        const float4* fr = reinterpret_cast<const float4*>(x + (size_t)src * 8);
        float4 a = fr[0], bb = fr[1];
        tx[0] += wv * a.x;  tx[1] += wv * a.y;  tx[2] += wv * a.z;  tx[3] += wv * a.w;
        tx[4] += wv * bb.x; tx[5] += wv * bb.y; tx[6] += wv * bb.z; tx[7] += wv * bb.w;
    }
#pragma unroll
    for (int i = 0; i < 8; ++i) {
        tx[i] += __shfl_xor(tx[i], 1);
        tx[i] += __shfl_xor(tx[i], 2);
    }
    float xa[8];
    const float4* xr = reinterpret_cast<const float4*>(x + (size_t)g * 8);
    float4 a = xr[0], bb = xr[1];
    xa[0] = a.x; xa[1] = a.y; xa[2] = a.z; xa[3] = a.w;
    xa[4] = bb.x; xa[5] = bb.y; xa[6] = bb.z; xa[7] = bb.w;
    float sc = -dis[g];
    int ob = sub * 4;
    float acc[4];
#pragma unroll
    for (int j = 0; j < 4; ++j) acc[j] = sb[ob + j];
#pragma unroll
    for (int f = 0; f < 8; ++f) {
        float xv = xa[f], tv = sc * tx[f];
#pragma unroll
        for (int j = 0; j < 4; ++j) acc[j] += xv * sW0[f * 16 + ob + j] + tv * sW1[f * 16 + ob + j];
    }
    float4 q;
    q.x = fmaxf(acc[0], 0.f); q.y = fmaxf(acc[1], 0.f);
    q.z = fmaxf(acc[2], 0.f); q.w = fmaxf(acc[3], 0.f);
    reinterpret_cast<float4*>(h1 + (size_t)g * 16)[sub] = q;
}

__global__ void gather_dense2_w4(const int* __restrict__ off, const int* __restrict__ csr_src,
                                 const float* __restrict__ dis, const float* __restrict__ h1,
                                 const float* __restrict__ W0, const float* __restrict__ W1,
                                 const float* __restrict__ b, const float* __restrict__ Wr,
                                 const float* __restrict__ br, float* __restrict__ s,
                                 int N, int E) {
    __shared__ float sW0[256], sW1[256], sb[16], sWr[16], sbr;
    for (int i = threadIdx.x; i < 256; i += blockDim.x) { sW0[i] = W0[i]; sW1[i] = W1[i]; }
    if (threadIdx.x < 16) { sb[threadIdx.x] = b[threadIdx.x]; sWr[threadIdx.x] = Wr[threadIdx.x]; }
    if (threadIdx.x == 0) sbr = br[0];
    __syncthreads();
    int t = blockIdx.x * blockDim.x + threadIdx.x;
    int g = t >> 2, sub = t & 3;
    if (g >= N) return;
    int p0 = off[g], p1 = (g == N - 1) ? E : off[g + 1];
    float tx[16];
#pragma unroll
    for (int o = 0; o < 16; ++o) tx[o] = 0.f;
    for (int p = p0 + sub; p < p1; p += 4) {
        int src = csr_src[p];
        float wv = dis[src];
        const float4* fr = reinterpret_cast<const float4*>(h1 + (size_t)src * 16);
#pragma unroll
        for (int v = 0; v < 4; ++v) {
            float4 q = fr[v];
            tx[v * 4 + 0] += wv * q.x;
            tx[v * 4 + 1] += wv * q.y;
            tx[v * 4 + 2] += wv * q.z;
            tx[v * 4 + 3] += wv * q.w;
        }
    }
#pragma unroll
    for (int i = 0; i < 16; ++i) {
        tx[i] += __shfl_xor(tx[i], 1);
        tx[i] += __shfl_xor(tx[i], 2);
    }
    float ha[16];
    const float4* hr = reinterpret_cast<const float4*>(h1 + (size_t)g * 16);
#pragma unroll
    for (int v = 0; v < 4; ++v) {
        float4 q = hr[v];
        ha[v * 4 + 0] = q.x; ha[v * 4 + 1] = q.y; ha[v * 4 + 2] = q.z; ha[v * 4 + 3] = q.w;
    }
    float sc = -dis[g];
    int ob = sub * 4;
    float acc[4];
#pragma unroll
    for (int j = 0; j < 4; ++j) acc[j] = sb[ob + j];
#pragma unroll
    for (int f = 0; f < 16; ++f) {
        float hv = ha[f], tv = sc * tx[f];
#pragma unroll
        for (int j = 0; j < 4; ++j) acc[j] += hv * sW0[f * 16 + ob + j] + tv * sW1[f * 16 + ob + j];
    }
    float sv = 0.f;
#pragma unroll
    for (int j = 0; j < 4; ++j) sv += fmaxf(acc[j], 0.f) * sWr[ob + j];
    sv += __shfl_xor(sv, 1);
    sv += __shfl_xor(sv, 2);
    if (sub == 0) s[g] = sv + sbr;
}

// ======================= launch =======================

extern "C" void kernel_launch(void* const* d_in, const int* in_sizes, int n_in,
                              void* d_out, int out_size, void* d_ws, size_t ws_size,
                              hipStream_t stream) {
    const float* x     = (const float*)d_in[0];
    const int*   ei    = (const int*)d_in[1];
    const int*   batch = (const int*)d_in[2];
    const float* W1_0  = (const float*)d_in[3];
    const float* W1_1  = (const float*)d_in[4];
    const float* b1    = (const float*)d_in[5];
    const float* W2_0  = (const float*)d_in[6];
    const float* W2_1  = (const float*)d_in[7];
    const float* b2    = (const float*)d_in[8];
    const float* Wr    = (const float*)d_in[9];
    const float* br    = (const float*)d_in[10];
    float* out = (float*)d_out;

    const int N = in_sizes[2];
    const int E = in_sizes[1] / 2;
    const int G = 256;
    const int* row = ei;
    const int* col = ei + E;

    const int gN = (N + THREADS - 1) / THREADS;
    const int gE = (E + THREADS - 1) / THREADS;
    const int gW = ((size_t)N * 4 + THREADS - 1) / THREADS;

    auto al = [](size_t v) { return (v + 255) & ~(size_t)255; };
    auto maxz = [](size_t a, size_t b) { return a > b ? a : b; };

    // -------- v10 layout --------
    const int NBIN  = (N + BINW - 1) >> SH;
    const int NGR   = (N + GWR4 - 1) >> SHR4;
    const int NBLK4 = (E + SCHUNK - 1) / SCHUNK;
    size_t rA1  = al((size_t)E * 4);
    size_t rB1H = al(maxz((size_t)E * 2, (size_t)80 * N));  // B1 ∪ h1s8(16B/n)+P0(64B/n)
    size_t rDIS = al((size_t)N * 4);
    size_t rS   = al((size_t)N * 4);
    size_t rXS  = al((size_t)16 * N);       // bf16 xs
    size_t rOFF = al((size_t)N * 4);
    size_t nHist = (size_t)NBLK4 * NBIN + NBIN + (NBIN + 1) +
                   (size_t)NBLK4 * NGR + NGR + (NGR + 1);
    size_t rHIST = al(nHist * 4);
    size_t need_v10 = rA1 + rB1H + rDIS + rS + rXS + rOFF + rHIST;

    if (N <= (1 << 18) && NBIN <= MAXBIN4 && NGR <= MAXGR4 && ws_size >= need_v10) {
        char* base = (char*)d_ws;
        unsigned int* A1   = (unsigned int*)base;
        unsigned short* B1 = (unsigned short*)(base + rA1);
        unsigned int* h1s8 = (unsigned int*)(base + rA1);    // after deg4 (16B/node)
        float* P0   = (float*)(base + rA1 + (size_t)16 * N);
        float* dis = (float*)(base + rA1 + rB1H);
        float* s   = (float*)(base + rA1 + rB1H + rDIS);
        uint4* xsb = (uint4*)(base + rA1 + rB1H + rDIS + rS);
        int* off   = (int*)(base + rA1 + rB1H + rDIS + rS + rXS);
        int* hist  = (int*)(base + rA1 + rB1H + rDIS + rS + rXS + rOFF);
        int* D2c  = hist;
        int* totC = D2c + (size_t)NBLK4 * NBIN;
        int* basC = totC + NBIN;
        int* D2r  = basC + NBIN + 1;
        int* totR = D2r + (size_t)NBLK4 * NGR;
        int* basR = totR + NGR;

        hist4_kernel<<<NBLK4, 512, 0, stream>>>(row, col, D2c, D2r, E, NBIN, NGR);
        scan_col2_kernel<<<NBIN + NGR, THREADS, 0, stream>>>(D2c, totC, NBIN, D2r, totR, NGR, NBLK4);
        scan_bins2_kernel<<<2, 1024, 0, stream>>>(totC, basC, NBIN, totR, basR, NGR);
        scatter_colS<<<NBLK4, 512, 0, stream>>>(row, col, D2c, totC, basC, A1, E, NBIN, NBLK4);
        scatter_rowS<<<NBLK4, 512, 0, stream>>>(row, D2r, totR, basR, B1, E, NGR, NBLK4);
        deg4_kernel<<<NGR, 1024, 0, stream>>>(B1, basR, x, dis, xsb, N);  // B1 dead after
        gather1S<<<NBIN, 1024, 0, stream>>>(A1, basC, xsb, x, dis, W1_0, W1_1, b1,
                                            W2_0, b2, h1s8, P0, off, N);
        gather2S<<<NBIN, 1024, 0, stream>>>(A1, basC, off, (const uint4*)h1s8, P0, dis,
                                            W2_1, Wr, br, s, N);
        softmax_kernel<<<G, THREADS, 0, stream>>>(s, batch, out, N);
    } else {
        // generic fallback: atomic CSR build + w4 gathers (fp32)
        int* deg_i = (int*)d_ws;
        int* cnt   = deg_i + N;
        int* fill  = cnt + N;
        int* off   = fill + N;
        int* bsum  = off + N;
        float* dis = (float*)(bsum + 1024);
        float* h1  = dis + N;
        float* s   = h1 + (size_t)16 * N;
        int* csr   = (int*)(s + N);

        hipMemsetAsync(deg_i, 0, sizeof(int) * (size_t)3 * N, stream);

        deg_cnt_kernel<<<gE, THREADS, 0, stream>>>(row, col, deg_i, cnt, E);
        dis_kernel_i<<<gN, THREADS, 0, stream>>>(deg_i, dis, N);
        scan1_kernel<<<gN, THREADS, 0, stream>>>(cnt, off, bsum, N);
        scan2_kernel<<<1, 1024, 0, stream>>>(bsum, gN);
        scan3_kernel<<<gN, THREADS, 0, stream>>>(off, bsum, N);
        fill_csr_kernel<<<gE, THREADS, 0, stream>>>(row, col, off, fill, csr, E);
        gather_dense1_w4<<<gW, THREADS, 0, stream>>>(off, csr, dis, x, W1_0, W1_1, b1, h1, N, E);
        gather_dense2_w4<<<gW, THREADS, 0, stream>>>(off, csr, dis, h1, W2_0, W2_1, b2, Wr, br, s, N, E);
        softmax_kernel<<<G, THREADS, 0, stream>>>(s, batch, out, N);
    }
}

// Round 16
// 404.506 us; speedup vs baseline: 1.0048x; 1.0048x over previous
//
#include <hip/hip_runtime.h>
#include <math.h>

#define THREADS 256

// ---- v11 parameters ----
#define SH 7                 // col-bin width 128
#define BINW 128
#define MAXBIN4 2048         // NBIN cap (N <= 262144)
#define SHR4 10              // row-group width 1024
#define GWR4 1024
#define MAXGR4 256
#define SCHUNK 16384         // edges per binning block
#define GCAP 9088            // gather LDS bucket capacity (~36KB; bucket mean 8192 + 9.9 sigma)
#define FP8S 64.0f
#define FP8SI (1.0f / 64.0f)

typedef float v2f __attribute__((ext_vector_type(2)));

// bf16 helpers (RNE)
__device__ inline unsigned short f2bf(float f) {
    unsigned int u = __float_as_uint(f);
    return (unsigned short)((u + 0x7FFFu + ((u >> 16) & 1u)) >> 16);
}
__device__ inline float bfLo(unsigned int u) { return __uint_as_float(u << 16); }
__device__ inline float bfHi(unsigned int u) { return __uint_as_float(u & 0xFFFF0000u); }

// fp8 e4m3 helpers (HW cvt, gfx950)
__device__ inline unsigned int pk4_fp8(float a, float b, float c, float d) {
    int u = __builtin_amdgcn_cvt_pk_fp8_f32(a, b, 0, false);
    u = __builtin_amdgcn_cvt_pk_fp8_f32(c, d, u, true);
    return (unsigned int)u;
}

// ======================= scans =======================

__device__ inline void scan_one_col(int* D, int* binTot, int NBLK, int NBIN, int b) {
    __shared__ int tmp[THREADS];
    int carry = 0;
    for (int base = 0; base < NBLK; base += THREADS) {
        int idx = base + threadIdx.x;
        int v = (idx < NBLK) ? D[(size_t)idx * NBIN + b] : 0;
        tmp[threadIdx.x] = v;
        __syncthreads();
        for (int d = 1; d < THREADS; d <<= 1) {
            int u = (threadIdx.x >= d) ? tmp[threadIdx.x - d] : 0;
            __syncthreads();
            tmp[threadIdx.x] += u;
            __syncthreads();
        }
        if (idx < NBLK) D[(size_t)idx * NBIN + b] = carry + tmp[threadIdx.x] - v;
        carry += tmp[THREADS - 1];
        __syncthreads();
    }
    if (threadIdx.x == 0) binTot[b] = carry;
}

__global__ void scan_col2_kernel(int* __restrict__ Dc, int* __restrict__ totC, int NBINc,
                                 int* __restrict__ Dr, int* __restrict__ totR, int NBINr,
                                 int NBLK) {
    int b = blockIdx.x;
    if (b < NBINc) scan_one_col(Dc, totC, NBLK, NBINc, b);
    else           scan_one_col(Dr, totR, NBLK, NBINr, b - NBINc);
}

__device__ inline void scan_bins_one(const int* binTot, int* binBase, int NBIN) {
    __shared__ int tmp[1024];
    int carry = 0;
    for (int base = 0; base < NBIN; base += 1024) {
        int i = base + threadIdx.x;
        int v = (i < NBIN) ? binTot[i] : 0;
        tmp[threadIdx.x] = v;
        __syncthreads();
        for (int d = 1; d < 1024; d <<= 1) {
            int u = (threadIdx.x >= d) ? tmp[threadIdx.x - d] : 0;
            __syncthreads();
            tmp[threadIdx.x] += u;
            __syncthreads();
        }
        if (i < NBIN) binBase[i] = carry + tmp[threadIdx.x] - v;
        carry += tmp[1023];
        __syncthreads();
    }
    if (threadIdx.x == 0) binBase[NBIN] = carry;
}

__global__ void scan_bins2_kernel(const int* __restrict__ totC, int* __restrict__ basC, int NBINc,
                                  const int* __restrict__ totR, int* __restrict__ basR, int NBINr) {
    if (blockIdx.x == 0) scan_bins_one(totC, basC, NBINc);
    else                 scan_bins_one(totR, basR, NBINr);
}

// ======================= v11 build =======================

__global__ __launch_bounds__(512) void hist4_kernel(const int* __restrict__ row,
                                                    const int* __restrict__ col,
                                                    int* __restrict__ D2c, int* __restrict__ D2r,
                                                    int E, int NBIN, int NGR) {
    __shared__ int hc[MAXBIN4], hr[MAXGR4];
    int t = threadIdx.x;
    for (int i = t; i < NBIN; i += 512) hc[i] = 0;
    for (int i = t; i < NGR; i += 512) hr[i] = 0;
    __syncthreads();
    int base = blockIdx.x * SCHUNK;
    int lim = min(SCHUNK, E - base);
    for (int k = t; k < lim; k += 512) {
        int e = base + k;
        atomicAdd(&hc[col[e] >> SH], 1);
        atomicAdd(&hr[row[e] >> SHR4], 1);
    }
    __syncthreads();
    for (int i = t; i < NBIN; i += 512) D2c[(size_t)blockIdx.x * NBIN + i] = hc[i];
    for (int i = t; i < NGR; i += 512) D2r[(size_t)blockIdx.x * NGR + i] = hr[i];
}

// col scatter: counts derived from scanned D2c deltas
__global__ __launch_bounds__(512) void scatter_colS(const int* __restrict__ row,
                                                    const int* __restrict__ col,
                                                    const int* __restrict__ D2c,
                                                    const int* __restrict__ totC,
                                                    const int* __restrict__ basC,
                                                    unsigned int* __restrict__ A1,
                                                    int E, int NBIN, int NBLK) {
    __shared__ unsigned int buf[SCHUNK];        // 64KB
    __shared__ int ls[MAXBIN4];                 // 8KB (starts -> ends)
    __shared__ unsigned short secbin[SCHUNK / 32];  // 1KB
    __shared__ int tmps[512];
    __shared__ int carry;
    int t = threadIdx.x;
    int base = blockIdx.x * SCHUNK;
    int lim = min(SCHUNK, E - base);
    const int* Dg  = D2c + (size_t)blockIdx.x * NBIN;
    const int* Dn  = (blockIdx.x == NBLK - 1) ? totC : Dg + NBIN;
    if (t == 0) carry = 0;
    __syncthreads();
    for (int cb = 0; cb < NBIN; cb += 512) {
        int idx = cb + t;
        int v = (idx < NBIN) ? (Dn[idx] - Dg[idx]) : 0;
        tmps[t] = v;
        __syncthreads();
        for (int d = 1; d < 512; d <<= 1) {
            int u = (t >= d) ? tmps[t - d] : 0;
            __syncthreads();
            tmps[t] += u;
            __syncthreads();
        }
        if (idx < NBIN) ls[idx] = carry + tmps[t] - v;
        __syncthreads();
        if (t == 0) carry += tmps[511];
        __syncthreads();
    }
    for (int k = t; k < lim; k += 512) {
        int e = base + k;
        int c = col[e], r = row[e];
        int bin = c >> SH;
        int p = atomicAdd(&ls[bin], 1);
        buf[p] = (unsigned int)r | ((unsigned int)(c & (BINW - 1)) << 18);
    }
    __syncthreads();
    {
        int pos = t * 32;
        if (pos < lim) {
            int lo = 0, hi = NBIN;
            while (lo < hi) { int mid = (lo + hi) >> 1; if (ls[mid] > pos) hi = mid; else lo = mid + 1; }
            secbin[t] = (unsigned short)lo;
        }
    }
    __syncthreads();
    for (int i = t; i < lim; i += 512) {
        int bin = secbin[i >> 5];
        while (ls[bin] <= i) ++bin;
        int start = (bin > 0) ? ls[bin - 1] : 0;
        A1[Dg[bin] + basC[bin] + (i - start)] = buf[i];
    }
}

// row scatter: counts from D2r deltas
__global__ __launch_bounds__(512) void scatter_rowS(const int* __restrict__ row,
                                                    const int* __restrict__ D2r,
                                                    const int* __restrict__ totR,
                                                    const int* __restrict__ basR,
                                                    unsigned short* __restrict__ B1,
                                                    int E, int NGR, int NBLK) {
    __shared__ unsigned short buf16[SCHUNK];   // 32KB
    __shared__ unsigned char gof[SCHUNK];      // 16KB
    __shared__ int cnt[MAXGR4], ls[MAXGR4], ob[MAXGR4];
    __shared__ int tmps[512];
    int t = threadIdx.x;
    int base = blockIdx.x * SCHUNK;
    int lim = min(SCHUNK, E - base);
    const int* Dg = D2r + (size_t)blockIdx.x * NGR;
    const int* Dn = (blockIdx.x == NBLK - 1) ? totR : Dg + NGR;
    int myv = 0;
    if (t < NGR) {
        int cur = Dg[t];
        myv = Dn[t] - cur;
        ob[t] = cur + basR[t];
        cnt[t] = 0;
    }
    tmps[t] = myv;
    __syncthreads();
    for (int d = 1; d < 512; d <<= 1) {
        int u = (t >= d) ? tmps[t - d] : 0;
        __syncthreads();
        tmps[t] += u;
        __syncthreads();
    }
    if (t < NGR) ls[t] = tmps[t] - myv;
    __syncthreads();
    for (int k = t; k < lim; k += 512) {
        int r = row[base + k];
        int g = r >> SHR4;
        int p = ls[g] + atomicAdd(&cnt[g], 1);
        buf16[p] = (unsigned short)(r & (GWR4 - 1));
        gof[p] = (unsigned char)g;
    }
    __syncthreads();
    for (int i = t; i < lim; i += 512) {
        int g = gof[i];
        B1[ob[g] + (i - ls[g])] = buf16[i];
    }
}

// per row-group out-degree histogram -> dis, fused xs_bf = bf16(dis*x)
__global__ void deg4_kernel(const unsigned short* __restrict__ B1,
                            const int* __restrict__ basR,
                            const float* __restrict__ x,
                            float* __restrict__ dis, uint4* __restrict__ xsb, int N) {
    __shared__ int cnt[GWR4];
    int b = blockIdx.x;
    for (int i = threadIdx.x; i < GWR4; i += blockDim.x) cnt[i] = 0;
    __syncthreads();
    int p0 = basR[b], p1 = basR[b + 1];
    for (int i = p0 + threadIdx.x; i < p1; i += blockDim.x)
        atomicAdd(&cnt[B1[i]], 1);
    __syncthreads();
    for (int i = threadIdx.x; i < GWR4; i += blockDim.x) {
        int node = (b << SHR4) + i;
        if (node < N) {
            int c = cnt[i];
            float d = c > 0 ? rsqrtf((float)c) : 0.f;
            dis[node] = d;
            const float4* xr = reinterpret_cast<const float4*>(x + (size_t)node * 8);
            float4 a = xr[0], bb = xr[1];
            uint4 o;
            o.x = (unsigned int)f2bf(d * a.x) | ((unsigned int)f2bf(d * a.y) << 16);
            o.y = (unsigned int)f2bf(d * a.z) | ((unsigned int)f2bf(d * a.w) << 16);
            o.z = (unsigned int)f2bf(d * bb.x) | ((unsigned int)f2bf(d * bb.y) << 16);
            o.w = (unsigned int)f2bf(d * bb.z) | ((unsigned int)f2bf(d * bb.w) << 16);
            xsb[node] = o;
        }
    }
}

// ======================= v11 fused sort+gather+dense (512-thread, 4 lanes/node) ===========

__global__ __launch_bounds__(512) void gather1S(unsigned int* __restrict__ A1,
                                                const int* __restrict__ basC,
                                                const uint4* __restrict__ xsb,
                                                const float* __restrict__ x,
                                                const float* __restrict__ dis,
                                                const float* __restrict__ W0,
                                                const float* __restrict__ W1,
                                                const float* __restrict__ b1,
                                                const float* __restrict__ W20,
                                                const float* __restrict__ b2,
                                                unsigned int* __restrict__ h1s8,
                                                float* __restrict__ P0,
                                                int* __restrict__ off, int N) {
    __shared__ unsigned int lsrc[GCAP];             // ~36KB
    __shared__ int cnt[BINW], fill[BINW], ls[BINW + 1], tmp2[BINW];
    __shared__ float sW0[128], sW1[128], sb1[16], sW20[256], sb2[16];
    int t = threadIdx.x, b = blockIdx.x;
    for (int i = t; i < 128; i += 512) { sW0[i] = W0[i]; sW1[i] = W1[i]; }
    for (int i = t; i < 256; i += 512) sW20[i] = W20[i];
    if (t < 16) { sb1[t] = b1[t]; sb2[t] = b2[t]; }
    if (t < BINW) { cnt[t] = 0; fill[t] = 0; }
    __syncthreads();
    int p0 = basC[b], p1 = basC[b + 1], sz = p1 - p0;

    if (sz <= GCAP) {
        for (int i = t; i < sz; i += 512)
            atomicAdd(&cnt[(A1[p0 + i] >> 18) & (BINW - 1)], 1);
        __syncthreads();
        {
            int v = (t < BINW) ? cnt[t] : 0;
            if (t < BINW) tmp2[t] = v;
            __syncthreads();
            for (int d = 1; d < BINW; d <<= 1) {
                int u = (t >= d && t < BINW) ? tmp2[t - d] : 0;
                __syncthreads();
                if (t < BINW) tmp2[t] += u;
                __syncthreads();
            }
            if (t < BINW) ls[t] = tmp2[t] - v;
            if (t == BINW - 1) ls[BINW] = tmp2[BINW - 1];
        }
        __syncthreads();
        for (int i = t; i < sz; i += 512) {
            unsigned int a = A1[p0 + i];
            int cl = (a >> 18) & (BINW - 1);
            lsrc[ls[cl] + atomicAdd(&fill[cl], 1)] = a;
        }
        __syncthreads();
        for (int i = t; i < sz; i += 512) A1[p0 + i] = lsrc[i];
        if (t < BINW) {
            int node = (b << SH) + t;
            if (node < N) off[node] = p0 + ls[t];
        }
        int n = t >> 2, sub = t & 3;
        int node = (b << SH) + n;
        if (node < N) {
            float tx[8] = {0, 0, 0, 0, 0, 0, 0, 0};
            for (int k = ls[n] + sub; k < ls[n + 1]; k += 4) {
                int r = (int)(lsrc[k] & 0x3FFFFu);
                uint4 q = xsb[r];
                tx[0] += bfLo(q.x); tx[1] += bfHi(q.x);
                tx[2] += bfLo(q.y); tx[3] += bfHi(q.y);
                tx[4] += bfLo(q.z); tx[5] += bfHi(q.z);
                tx[6] += bfLo(q.w); tx[7] += bfHi(q.w);
            }
#pragma unroll
            for (int i = 0; i < 8; ++i) {
                tx[i] += __shfl_xor(tx[i], 1);
                tx[i] += __shfl_xor(tx[i], 2);
            }
            float d = dis[node], sc = -d;
            float xa[8];
            const float4* xr = reinterpret_cast<const float4*>(x + (size_t)node * 8);
            float4 a = xr[0], bb = xr[1];
            xa[0] = a.x; xa[1] = a.y; xa[2] = a.z; xa[3] = a.w;
            xa[4] = bb.x; xa[5] = bb.y; xa[6] = bb.z; xa[7] = bb.w;
            int ob = sub * 4;
            float acc[4];
#pragma unroll
            for (int j = 0; j < 4; ++j) acc[j] = sb1[ob + j];
#pragma unroll
            for (int f = 0; f < 8; ++f) {
                float xv = xa[f], tv = sc * tx[f];
#pragma unroll
                for (int j = 0; j < 4; ++j)
                    acc[j] += xv * sW0[f * 16 + ob + j] + tv * sW1[f * 16 + ob + j];
            }
            float h[4];
#pragma unroll
            for (int j = 0; j < 4; ++j) h[j] = fmaxf(acc[j], 0.f);
            float ds = d * FP8S;
            h1s8[(size_t)node * 4 + sub] = pk4_fp8(ds * h[0], ds * h[1], ds * h[2], ds * h[3]);
            float hall[16];
#pragma unroll
            for (int src = 0; src < 4; ++src) {
#pragma unroll
                for (int j = 0; j < 4; ++j) hall[src * 4 + j] = __shfl(h[j], src, 4);
            }
            float pp[4];
#pragma unroll
            for (int j = 0; j < 4; ++j) pp[j] = sb2[ob + j];
#pragma unroll
            for (int f = 0; f < 16; ++f) {
                float hv = hall[f];
#pragma unroll
                for (int j = 0; j < 4; ++j) pp[j] += hv * sW20[f * 16 + ob + j];
            }
            reinterpret_cast<float4*>(P0 + (size_t)node * 16)[sub] =
                make_float4(pp[0], pp[1], pp[2], pp[3]);
        }
    } else {
        // oversized bin (not expected): LDS f32-atomic accumulation; still writes off[]
        float* txf = (float*)lsrc;   // [BINW][9]
        for (int i = t; i < BINW * 9; i += 512) txf[i] = 0.f;
        __syncthreads();
        for (int i = t; i < sz; i += 512) {
            unsigned int a = A1[p0 + i];
            int r = a & 0x3FFFF, cl = (a >> 18) & (BINW - 1);
            atomicAdd(&cnt[cl], 1);
            uint4 q = xsb[r];
            atomicAdd(&txf[cl * 9 + 0], bfLo(q.x)); atomicAdd(&txf[cl * 9 + 1], bfHi(q.x));
            atomicAdd(&txf[cl * 9 + 2], bfLo(q.y)); atomicAdd(&txf[cl * 9 + 3], bfHi(q.y));
            atomicAdd(&txf[cl * 9 + 4], bfLo(q.z)); atomicAdd(&txf[cl * 9 + 5], bfHi(q.z));
            atomicAdd(&txf[cl * 9 + 6], bfLo(q.w)); atomicAdd(&txf[cl * 9 + 7], bfHi(q.w));
        }
        __syncthreads();
        if (t == 0) { int a = 0; for (int i = 0; i < BINW; ++i) { ls[i] = a; a += cnt[i]; } }
        __syncthreads();
        if (t < BINW) {
            int node = (b << SH) + t;
            if (node < N) {
                off[node] = p0 + ls[t];
                float d = dis[node], sc = -d;
                float xa[8];
                const float4* xr = reinterpret_cast<const float4*>(x + (size_t)node * 8);
                float4 a = xr[0], bb = xr[1];
                xa[0] = a.x; xa[1] = a.y; xa[2] = a.z; xa[3] = a.w;
                xa[4] = bb.x; xa[5] = bb.y; xa[6] = bb.z; xa[7] = bb.w;
                float acc[16];
#pragma unroll
                for (int o = 0; o < 16; ++o) acc[o] = sb1[o];
#pragma unroll
                for (int f = 0; f < 8; ++f) {
                    float xv = xa[f], tv = sc * txf[t * 9 + f];
#pragma unroll
                    for (int o = 0; o < 16; ++o)
                        acc[o] += xv * sW0[f * 16 + o] + tv * sW1[f * 16 + o];
                }
                float h[16];
#pragma unroll
                for (int o = 0; o < 16; ++o) h[o] = fmaxf(acc[o], 0.f);
                float ds = d * FP8S;
#pragma unroll
                for (int v = 0; v < 4; ++v)
                    h1s8[(size_t)node * 4 + v] = pk4_fp8(ds * h[v * 4 + 0], ds * h[v * 4 + 1],
                                                         ds * h[v * 4 + 2], ds * h[v * 4 + 3]);
                float pp[16];
#pragma unroll
                for (int o = 0; o < 16; ++o) pp[o] = sb2[o];
#pragma unroll
                for (int f = 0; f < 16; ++f) {
                    float hv = h[f];
#pragma unroll
                    for (int o = 0; o < 16; ++o) pp[o] += hv * sW20[f * 16 + o];
                }
                float4* po = reinterpret_cast<float4*>(P0 + (size_t)node * 16);
#pragma unroll
                for (int v = 0; v < 4; ++v)
                    po[v] = make_float4(pp[v * 4], pp[v * 4 + 1], pp[v * 4 + 2], pp[v * 4 + 3]);
            }
        }
    }
}

__global__ __launch_bounds__(512) void gather2S(const unsigned int* __restrict__ A1,
                                                const int* __restrict__ basC,
                                                const int* __restrict__ off,
                                                const uint4* __restrict__ h1s8,
                                                const float* __restrict__ P0,
                                                const float* __restrict__ dis,
                                                const float* __restrict__ W21,
                                                const float* __restrict__ Wr,
                                                const float* __restrict__ br,
                                                float* __restrict__ s, int N) {
    __shared__ unsigned int lsrc[GCAP];
    __shared__ float sW1[256], sWr[16], sbr;
    int t = threadIdx.x, b = blockIdx.x;
    for (int i = t; i < 256; i += 512) sW1[i] = W21[i];
    if (t < 16) sWr[t] = Wr[t];
    if (t == 0) sbr = br[0];
    __syncthreads();
    int p0 = basC[b], p1 = basC[b + 1], sz = p1 - p0;

    if (sz <= GCAP) {
        for (int i = t; i < sz; i += 512) lsrc[i] = __builtin_nontemporal_load(&A1[p0 + i]);
        __syncthreads();
        int n = t >> 2, sub = t & 3;
        int node = (b << SH) + n;
        if (node < N) {
            int st = off[node] - p0;
            int en = (n == BINW - 1 || node == N - 1) ? sz : off[node + 1] - p0;
            float tx[16];
#pragma unroll
            for (int o = 0; o < 16; ++o) tx[o] = 0.f;
            for (int k = st + sub; k < en; k += 4) {
                int r = (int)(lsrc[k] & 0x3FFFFu);
                uint4 q = h1s8[r];
                v2f p;
                p = __builtin_amdgcn_cvt_pk_f32_fp8((int)q.x, false); tx[0]  += p.x; tx[1]  += p.y;
                p = __builtin_amdgcn_cvt_pk_f32_fp8((int)q.x, true);  tx[2]  += p.x; tx[3]  += p.y;
                p = __builtin_amdgcn_cvt_pk_f32_fp8((int)q.y, false); tx[4]  += p.x; tx[5]  += p.y;
                p = __builtin_amdgcn_cvt_pk_f32_fp8((int)q.y, true);  tx[6]  += p.x; tx[7]  += p.y;
                p = __builtin_amdgcn_cvt_pk_f32_fp8((int)q.z, false); tx[8]  += p.x; tx[9]  += p.y;
                p = __builtin_amdgcn_cvt_pk_f32_fp8((int)q.z, true);  tx[10] += p.x; tx[11] += p.y;
                p = __builtin_amdgcn_cvt_pk_f32_fp8((int)q.w, false); tx[12] += p.x; tx[13] += p.y;
                p = __builtin_amdgcn_cvt_pk_f32_fp8((int)q.w, true);  tx[14] += p.x; tx[15] += p.y;
            }
#pragma unroll
            for (int i = 0; i < 16; ++i) {
                tx[i] += __shfl_xor(tx[i], 1);
                tx[i] += __shfl_xor(tx[i], 2);
            }
            float sc = -dis[node] * FP8SI;
            int ob = sub * 4;
            float4 pq = reinterpret_cast<const float4*>(P0 + (size_t)node * 16)[sub];
            float acc[4] = {pq.x, pq.y, pq.z, pq.w};
#pragma unroll
            for (int f = 0; f < 16; ++f) {
                float tv = sc * tx[f];
#pragma unroll
                for (int j = 0; j < 4; ++j) acc[j] += tv * sW1[f * 16 + ob + j];
            }
            float sv = 0.f;
#pragma unroll
            for (int j = 0; j < 4; ++j) sv += fmaxf(acc[j], 0.f) * sWr[ob + j];
            sv += __shfl_xor(sv, 1);
            sv += __shfl_xor(sv, 2);
            if (sub == 0) s[node] = sv + sbr;
        }
    } else {
        float* txf = (float*)lsrc;   // [BINW][17]
        for (int i = t; i < BINW * 17; i += 512) txf[i] = 0.f;
        __syncthreads();
        for (int i = t; i < sz; i += 512) {
            unsigned int a = A1[p0 + i];
            int r = a & 0x3FFFF, cl = (a >> 18) & (BINW - 1);
            uint4 q = h1s8[r];
            v2f p;
            p = __builtin_amdgcn_cvt_pk_f32_fp8((int)q.x, false);
            atomicAdd(&txf[cl * 17 + 0], p.x);  atomicAdd(&txf[cl * 17 + 1], p.y);
            p = __builtin_amdgcn_cvt_pk_f32_fp8((int)q.x, true);
            atomicAdd(&txf[cl * 17 + 2], p.x);  atomicAdd(&txf[cl * 17 + 3], p.y);
            p = __builtin_amdgcn_cvt_pk_f32_fp8((int)q.y, false);
            atomicAdd(&txf[cl * 17 + 4], p.x);  atomicAdd(&txf[cl * 17 + 5], p.y);
            p = __builtin_amdgcn_cvt_pk_f32_fp8((int)q.y, true);
            atomicAdd(&txf[cl * 17 + 6], p.x);  atomicAdd(&txf[cl * 17 + 7], p.y);
            p = __builtin_amdgcn_cvt_pk_f32_fp8((int)q.z, false);
            atomicAdd(&txf[cl * 17 + 8], p.x);  atomicAdd(&txf[cl * 17 + 9], p.y);
            p = __builtin_amdgcn_cvt_pk_f32_fp8((int)q.z, true);
            atomicAdd(&txf[cl * 17 + 10], p.x); atomicAdd(&txf[cl * 17 + 11], p.y);
            p = __builtin_amdgcn_cvt_pk_f32_fp8((int)q.w, false);
            atomicAdd(&txf[cl * 17 + 12], p.x); atomicAdd(&txf[cl * 17 + 13], p.y);
            p = __builtin_amdgcn_cvt_pk_f32_fp8((int)q.w, true);
            atomicAdd(&txf[cl * 17 + 14], p.x); atomicAdd(&txf[cl * 17 + 15], p.y);
        }
        __syncthreads();
        if (t < BINW) {
            int node = (b << SH) + t;
            if (node < N) {
                float sc = -dis[node] * FP8SI;
                float acc[16];
                const float4* pr = reinterpret_cast<const float4*>(P0 + (size_t)node * 16);
#pragma unroll
                for (int v = 0; v < 4; ++v) {
                    float4 q = pr[v];
                    acc[v * 4 + 0] = q.x; acc[v * 4 + 1] = q.y;
                    acc[v * 4 + 2] = q.z; acc[v * 4 + 3] = q.w;
                }
#pragma unroll
                for (int f = 0; f < 16; ++f) {
                    float tv = sc * txf[t * 17 + f];
#pragma unroll
                    for (int o = 0; o < 16; ++o) acc[o] += tv * sW1[f * 16 + o];
                }
                float sv = sbr;
#pragma unroll
                for (int o = 0; o < 16; ++o) sv += fmaxf(acc[o], 0.f) * sWr[o];
                s[node] = sv;
            }
        }
    }
}

__global__ void softmax_kernel(const float* __restrict__ s, const int* __restrict__ batch,
                               float* __restrict__ out, int N) {
    int g = blockIdx.x;
    __shared__ float red[THREADS];
    int lo, hi;
    { int a = 0, b = N; while (a < b) { int mid = (a + b) >> 1; if (batch[mid] < g) a = mid + 1; else b = mid; } lo = a; }
    { int a = lo, b = N; while (a < b) { int mid = (a + b) >> 1; if (batch[mid] < g + 1) a = mid + 1; else b = mid; } hi = a; }
    float mx = -INFINITY;
    for (int i = lo + threadIdx.x; i < hi; i += THREADS) mx = fmaxf(mx, s[i]);
    red[threadIdx.x] = mx;
    __syncthreads();
    for (int d = THREADS / 2; d > 0; d >>= 1) {
        if (threadIdx.x < d) red[threadIdx.x] = fmaxf(red[threadIdx.x], red[threadIdx.x + d]);
        __syncthreads();
    }
    mx = red[0];
    __syncthreads();
    float sum = 0.f;
    for (int i = lo + threadIdx.x; i < hi; i += THREADS) sum += expf(s[i] - mx);
    red[threadIdx.x] = sum;
    __syncthreads();
    for (int d = THREADS / 2; d > 0; d >>= 1) {
        if (threadIdx.x < d) red[threadIdx.x] += red[threadIdx.x + d];
        __syncthreads();
    }
    float inv = 1.f / red[0];
    for (int i = lo + threadIdx.x; i < hi; i += THREADS) out[i] = expf(s[i] - mx) * inv;
}

// ======================= generic fallback (round-2 CSR + w4 gathers, fp32) =======================

__global__ void deg_cnt_kernel(const int* __restrict__ row, const int* __restrict__ col,
                               int* __restrict__ deg_i, int* __restrict__ cnt, int E) {
    int e = blockIdx.x * blockDim.x + threadIdx.x;
    if (e >= E) return;
    atomicAdd(&deg_i[row[e]], 1);
    atomicAdd(&cnt[col[e]], 1);
}

__global__ void dis_kernel_i(const int* __restrict__ deg_i, float* __restrict__ dis, int N) {
    int i = blockIdx.x * blockDim.x + threadIdx.x;
    if (i < N) {
        int d = deg_i[i];
        dis[i] = d > 0 ? rsqrtf((float)d) : 0.f;
    }
}

__global__ void scan1_kernel(const int* __restrict__ cnt, int* __restrict__ off,
                             int* __restrict__ bsum, int n) {
    __shared__ int tmp[THREADS];
    int i = blockIdx.x * THREADS + threadIdx.x;
    int v = (i < n) ? cnt[i] : 0;
    tmp[threadIdx.x] = v;
    __syncthreads();
    for (int d = 1; d < THREADS; d <<= 1) {
        int t = (threadIdx.x >= d) ? tmp[threadIdx.x - d] : 0;
        __syncthreads();
        tmp[threadIdx.x] += t;
        __syncthreads();
    }
    if (i < n) off[i] = tmp[threadIdx.x] - v;
    if (threadIdx.x == THREADS - 1) bsum[blockIdx.x] = tmp[threadIdx.x];
}

__global__ void scan2_kernel(int* __restrict__ bsum, int nb) {
    __shared__ int tmp[1024];
    int carry = 0;
    for (int base = 0; base < nb; base += 1024) {
        int i = base + threadIdx.x;
        int v = (i < nb) ? bsum[i] : 0;
        tmp[threadIdx.x] = v;
        __syncthreads();
        for (int d = 1; d < 1024; d <<= 1) {
            int t = (threadIdx.x >= d) ? tmp[threadIdx.x - d] : 0;
            __syncthreads();
            tmp[threadIdx.x] += t;
            __syncthreads();
        }
        if (i < nb) bsum[i] = carry + tmp[threadIdx.x] - v;
        carry += tmp[1023];
        __syncthreads();
    }
}

__global__ void scan3_kernel(int* __restrict__ off, const int* __restrict__ bsum, int n) {
    int i = blockIdx.x * THREADS + threadIdx.x;
    if (i < n) off[i] += bsum[blockIdx.x];
}

__global__ void fill_csr_kernel(const int* __restrict__ row, const int* __restrict__ col,
                                const int* __restrict__ off, int* __restrict__ fill,
                                int* __restrict__ csr_src, int E) {
    int e = blockIdx.x * blockDim.x + threadIdx.x;
    if (e >= E) return;
    int c = col[e];
    int p = off[c] + atomicAdd(&fill[c], 1);
    csr_src[p] = row[e];
}

__global__ void gather_dense1_w4(const int* __restrict__ off, const int* __restrict__ csr_src,
                                 const float* __restrict__ dis, const float* __restrict__ x,
                                 const float* __restrict__ W0, const float* __restrict__ W1,
                                 const float* __restrict__ b, float* __restrict__ h1,
                                 int N, int E) {
    __shared__ float sW0[128], sW1[128], sb[16];
    for (int i = threadIdx.x; i < 128; i += blockDim.x) { sW0[i] = W0[i]; sW1[i] = W1[i]; }
    if (threadIdx.x < 16) sb[threadIdx.x] = b[threadIdx.x];
    __syncthreads();
    int t = blockIdx.x * blockDim.x + threadIdx.x;
    int g = t >> 2, sub = t & 3;
    if (g >= N) return;
    int p0 = off[g], p1 = (g == N - 1) ? E : off[g + 1];
    float tx[8] = {0, 0, 0, 0, 0, 0, 0, 0};
    for (int p = p0 + sub; p < p1; p += 4) {
        int src = csr_src[p];
        float wv = dis[src];
        const float4* fr = reinterpret_cast<const float4*>(x + (size_t)src * 8);
        float4 a = fr[0], bb = fr[1];
        tx[0] += wv * a.x;  tx[1] += wv * a.y;  tx[2] += wv * a.z;  tx[3] += wv * a.w;
        tx[4] += wv * bb.x; tx[5] += wv * bb.y; tx[6] += wv * bb.z; tx[7] += wv * bb.w;
    }
#pragma unroll
    for (int i = 0; i < 8; ++i) {
        tx[i] += __shfl_xor(tx[i], 1);
        tx[i] += __shfl_xor(tx[i], 2);
    }
    float xa[8];
    const float4* xr = reinterpret_cast<const float4*>(x + (size_t)g * 8);
    float4 a = xr[0], bb = xr[1];
    xa[0] = a.x; xa[1] = a.y; xa[2] = a.z; xa[3] = a.w;
    xa[4] = bb.x; xa[5] = bb.y; xa[6] = bb.z; xa[7] = bb.w;
    float sc = -dis[g];
    int ob = sub * 4;
    float acc[4];
#pragma unroll
    for (int j = 0; j < 4; ++j) acc[j] = sb[ob + j];
#pragma unroll
    for (int f = 0; f < 8; ++f) {
        float xv = xa[f], tv = sc * tx[f];
#pragma unroll
        for (int j = 0; j < 4; ++j) acc[j] += xv * sW0[f * 16 + ob + j] + tv * sW1[f * 16 + ob + j];
    }
    float4 q;
    q.x = fmaxf(acc[0], 0.f); q.y = fmaxf(acc[1], 0.f);
    q.z = fmaxf(acc[2], 0.f); q.w = fmaxf(acc[3], 0.f);
    reinterpret_cast<float4*>(h1 + (size_t)g * 16)[sub] = q;
}

__global__ void gather_dense2_w4(const int* __restrict__ off, const int* __restrict__ csr_src,
                                 const float* __restrict__ dis, const float* __restrict__ h1,
                                 const float* __restrict__ W0, const float* __restrict__ W1,
                                 const float* __restrict__ b, const float* __restrict__ Wr,
                                 const float* __restrict__ br, float* __restrict__ s,
                                 int N, int E) {
    __shared__ float sW0[256], sW1[256], sb[16], sWr[16], sbr;
    for (int i = threadIdx.x; i < 256; i += blockDim.x) { sW0[i] = W0[i]; sW1[i] = W1[i]; }
    if (threadIdx.x < 16) { sb[threadIdx.x] = b[threadIdx.x]; sWr[threadIdx.x] = Wr[threadIdx.x]; }
    if (threadIdx.x == 0) sbr = br[0];
    __syncthreads();
    int t = blockIdx.x * blockDim.x + threadIdx.x;
    int g = t >> 2, sub = t & 3;
    if (g >= N) return;
    int p0 = off[g], p1 = (g == N - 1) ? E : off[g + 1];
    float tx[16];
#pragma unroll
    for (int o = 0; o < 16; ++o) tx[o] = 0.f;
    for (int p = p0 + sub; p < p1; p += 4) {
        int src = csr_src[p];
        float wv = dis[src];
        const float4* fr = reinterpret_cast<const float4*>(h1 + (size_t)src * 16);
#pragma unroll
        for (int v = 0; v < 4; ++v) {
            float4 q = fr[v];
            tx[v * 4 + 0] += wv * q.x;
            tx[v * 4 + 1] += wv * q.y;
            tx[v * 4 + 2] += wv * q.z;
            tx[v * 4 + 3] += wv * q.w;
        }
    }
#pragma unroll
    for (int i = 0; i < 16; ++i) {
        tx[i] += __shfl_xor(tx[i], 1);
        tx[i] += __shfl_xor(tx[i], 2);
    }
    float ha[16];
    const float4* hr = reinterpret_cast<const float4*>(h1 + (size_t)g * 16);
#pragma unroll
    for (int v = 0; v < 4; ++v) {
        float4 q = hr[v];
        ha[v * 4 + 0] = q.x; ha[v * 4 + 1] = q.y; ha[v * 4 + 2] = q.z; ha[v * 4 + 3] = q.w;
    }
    float sc = -dis[g];
    int ob = sub * 4;
    float acc[4];
#pragma unroll
    for (int j = 0; j < 4; ++j) acc[j] = sb[ob + j];
#pragma unroll
    for (int f = 0; f < 16; ++f) {
        float hv = ha[f], tv = sc * tx[f];
#pragma unroll
        for (int j = 0; j < 4; ++j) acc[j] += hv * sW0[f * 16 + ob + j] + tv * sW1[f * 16 + ob + j];
    }
    float sv = 0.f;
#pragma unroll
    for (int j = 0; j < 4; ++j) sv += fmaxf(acc[j], 0.f) * sWr[ob + j];
    sv += __shfl_xor(sv, 1);
    sv += __shfl_xor(sv, 2);
    if (sub == 0) s[g] = sv + sbr;
}

// ======================= launch =======================

extern "C" void kernel_launch(void* const* d_in, const int* in_sizes, int n_in,
                              void* d_out, int out_size, void* d_ws, size_t ws_size,
                              hipStream_t stream) {
    const float* x     = (const float*)d_in[0];
    const int*   ei    = (const int*)d_in[1];
    const int*   batch = (const int*)d_in[2];
    const float* W1_0  = (const float*)d_in[3];
    const float* W1_1  = (const float*)d_in[4];
    const float* b1    = (const float*)d_in[5];
    const float* W2_0  = (const float*)d_in[6];
    const float* W2_1  = (const float*)d_in[7];
    const float* b2    = (const float*)d_in[8];
    const float* Wr    = (const float*)d_in[9];
    const float* br    = (const float*)d_in[10];
    float* out = (float*)d_out;

    const int N = in_sizes[2];
    const int E = in_sizes[1] / 2;
    const int G = 256;
    const int* row = ei;
    const int* col = ei + E;

    const int gN = (N + THREADS - 1) / THREADS;
    const int gE = (E + THREADS - 1) / THREADS;
    const int gW = ((size_t)N * 4 + THREADS - 1) / THREADS;

    auto al = [](size_t v) { return (v + 255) & ~(size_t)255; };
    auto maxz = [](size_t a, size_t b) { return a > b ? a : b; };

    // -------- v11 layout --------
    const int NBIN  = (N + BINW - 1) >> SH;
    const int NGR   = (N + GWR4 - 1) >> SHR4;
    const int NBLK4 = (E + SCHUNK - 1) / SCHUNK;
    size_t rA1  = al((size_t)E * 4);
    size_t rB1H = al(maxz((size_t)E * 2, (size_t)80 * N));  // B1 ∪ h1s8(16B/n)+P0(64B/n)
    size_t rDIS = al((size_t)N * 4);
    size_t rS   = al((size_t)N * 4);
    size_t rXS  = al((size_t)16 * N);       // bf16 xs
    size_t rOFF = al((size_t)N * 4);
    size_t nHist = (size_t)NBLK4 * NBIN + NBIN + (NBIN + 1) +
                   (size_t)NBLK4 * NGR + NGR + (NGR + 1);
    size_t rHIST = al(nHist * 4);
    size_t need_v11 = rA1 + rB1H + rDIS + rS + rXS + rOFF + rHIST;

    if (N <= (1 << 18) && NBIN <= MAXBIN4 && NGR <= MAXGR4 && ws_size >= need_v11) {
        char* base = (char*)d_ws;
        unsigned int* A1   = (unsigned int*)base;
        unsigned short* B1 = (unsigned short*)(base + rA1);
        unsigned int* h1s8 = (unsigned int*)(base + rA1);    // after deg4 (16B/node)
        float* P0   = (float*)(base + rA1 + (size_t)16 * N);
        float* dis = (float*)(base + rA1 + rB1H);
        float* s   = (float*)(base + rA1 + rB1H + rDIS);
        uint4* xsb = (uint4*)(base + rA1 + rB1H + rDIS + rS);
        int* off   = (int*)(base + rA1 + rB1H + rDIS + rS + rXS);
        int* hist  = (int*)(base + rA1 + rB1H + rDIS + rS + rXS + rOFF);
        int* D2c  = hist;
        int* totC = D2c + (size_t)NBLK4 * NBIN;
        int* basC = totC + NBIN;
        int* D2r  = basC + NBIN + 1;
        int* totR = D2r + (size_t)NBLK4 * NGR;
        int* basR = totR + NGR;

        hist4_kernel<<<NBLK4, 512, 0, stream>>>(row, col, D2c, D2r, E, NBIN, NGR);
        scan_col2_kernel<<<NBIN + NGR, THREADS, 0, stream>>>(D2c, totC, NBIN, D2r, totR, NGR, NBLK4);
        scan_bins2_kernel<<<2, 1024, 0, stream>>>(totC, basC, NBIN, totR, basR, NGR);
        scatter_colS<<<NBLK4, 512, 0, stream>>>(row, col, D2c, totC, basC, A1, E, NBIN, NBLK4);
        scatter_rowS<<<NBLK4, 512, 0, stream>>>(row, D2r, totR, basR, B1, E, NGR, NBLK4);
        deg4_kernel<<<NGR, 1024, 0, stream>>>(B1, basR, x, dis, xsb, N);  // B1 dead after
        gather1S<<<NBIN, 512, 0, stream>>>(A1, basC, xsb, x, dis, W1_0, W1_1, b1,
                                           W2_0, b2, h1s8, P0, off, N);
        gather2S<<<NBIN, 512, 0, stream>>>(A1, basC, off, (const uint4*)h1s8, P0, dis,
                                           W2_1, Wr, br, s, N);
        softmax_kernel<<<G, THREADS, 0, stream>>>(s, batch, out, N);
    } else {
        // generic fallback: atomic CSR build + w4 gathers (fp32)
        int* deg_i = (int*)d_ws;
        int* cnt   = deg_i + N;
        int* fill  = cnt + N;
        int* off   = fill + N;
        int* bsum  = off + N;
        float* dis = (float*)(bsum + 1024);
        float* h1  = dis + N;
        float* s   = h1 + (size_t)16 * N;
        int* csr   = (int*)(s + N);

        hipMemsetAsync(deg_i, 0, sizeof(int) * (size_t)3 * N, stream);

        deg_cnt_kernel<<<gE, THREADS, 0, stream>>>(row, col, deg_i, cnt, E);
        dis_kernel_i<<<gN, THREADS, 0, stream>>>(deg_i, dis, N);
        scan1_kernel<<<gN, THREADS, 0, stream>>>(cnt, off, bsum, N);
        scan2_kernel<<<1, 1024, 0, stream>>>(bsum, gN);
        scan3_kernel<<<gN, THREADS, 0, stream>>>(off, bsum, N);
        fill_csr_kernel<<<gE, THREADS, 0, stream>>>(row, col, off, fill, csr, E);
        gather_dense1_w4<<<gW, THREADS, 0, stream>>>(off, csr, dis, x, W1_0, W1_1, b1, h1, N, E);
        gather_dense2_w4<<<gW, THREADS, 0, stream>>>(off, csr, dis, h1, W2_0, W2_1, b2, Wr, br, s, N, E);
        softmax_kernel<<<G, THREADS, 0, stream>>>(s, batch, out, N);
    }
}

// Round 17
// 370.547 us; speedup vs baseline: 1.0969x; 1.0916x over previous
//
#include <hip/hip_runtime.h>
#include <math.h>

#define THREADS 256

// ---- v9 parameters (round-14 proven configuration) ----
#define SH 7                 // col-bin width 128
#define BINW 128
#define MAXBIN4 2048         // NBIN cap (N <= 262144)
#define SHR4 10              // row-group width 1024
#define GWR4 1024
#define MAXGR4 256
#define SCHUNK 16384         // edges per binning block
#define GCAP 10240           // gather LDS bucket capacity (40KB; max bucket ~8.5K)
#define FP8S 64.0f
#define FP8SI (1.0f / 64.0f)

typedef float v2f __attribute__((ext_vector_type(2)));

// bf16 helpers (RNE)
__device__ inline unsigned short f2bf(float f) {
    unsigned int u = __float_as_uint(f);
    return (unsigned short)((u + 0x7FFFu + ((u >> 16) & 1u)) >> 16);
}
__device__ inline float bfLo(unsigned int u) { return __uint_as_float(u << 16); }
__device__ inline float bfHi(unsigned int u) { return __uint_as_float(u & 0xFFFF0000u); }

// fp8 e4m3 helpers (HW cvt, gfx950)
__device__ inline unsigned int pk4_fp8(float a, float b, float c, float d) {
    int u = __builtin_amdgcn_cvt_pk_fp8_f32(a, b, 0, false);
    u = __builtin_amdgcn_cvt_pk_fp8_f32(c, d, u, true);
    return (unsigned int)u;
}

// ======================= scans =======================

__device__ inline void scan_one_col(int* D, int* binTot, int NBLK, int NBIN, int b) {
    __shared__ int tmp[THREADS];
    int carry = 0;
    for (int base = 0; base < NBLK; base += THREADS) {
        int idx = base + threadIdx.x;
        int v = (idx < NBLK) ? D[(size_t)idx * NBIN + b] : 0;
        tmp[threadIdx.x] = v;
        __syncthreads();
        for (int d = 1; d < THREADS; d <<= 1) {
            int u = (threadIdx.x >= d) ? tmp[threadIdx.x - d] : 0;
            __syncthreads();
            tmp[threadIdx.x] += u;
            __syncthreads();
        }
        if (idx < NBLK) D[(size_t)idx * NBIN + b] = carry + tmp[threadIdx.x] - v;
        carry += tmp[THREADS - 1];
        __syncthreads();
    }
    if (threadIdx.x == 0) binTot[b] = carry;
}

__global__ void scan_col2_kernel(int* __restrict__ Dc, int* __restrict__ totC, int NBINc,
                                 int* __restrict__ Dr, int* __restrict__ totR, int NBINr,
                                 int NBLK) {
    int b = blockIdx.x;
    if (b < NBINc) scan_one_col(Dc, totC, NBLK, NBINc, b);
    else           scan_one_col(Dr, totR, NBLK, NBINr, b - NBINc);
}

__device__ inline void scan_bins_one(const int* binTot, int* binBase, int NBIN) {
    __shared__ int tmp[1024];
    int carry = 0;
    for (int base = 0; base < NBIN; base += 1024) {
        int i = base + threadIdx.x;
        int v = (i < NBIN) ? binTot[i] : 0;
        tmp[threadIdx.x] = v;
        __syncthreads();
        for (int d = 1; d < 1024; d <<= 1) {
            int u = (threadIdx.x >= d) ? tmp[threadIdx.x - d] : 0;
            __syncthreads();
            tmp[threadIdx.x] += u;
            __syncthreads();
        }
        if (i < NBIN) binBase[i] = carry + tmp[threadIdx.x] - v;
        carry += tmp[1023];
        __syncthreads();
    }
    if (threadIdx.x == 0) binBase[NBIN] = carry;
}

__global__ void scan_bins2_kernel(const int* __restrict__ totC, int* __restrict__ basC, int NBINc,
                                  const int* __restrict__ totR, int* __restrict__ basR, int NBINr) {
    if (blockIdx.x == 0) scan_bins_one(totC, basC, NBINc);
    else                 scan_bins_one(totR, basR, NBINr);
}

// ======================= build =======================

__global__ __launch_bounds__(512) void hist4_kernel(const int* __restrict__ row,
                                                    const int* __restrict__ col,
                                                    int* __restrict__ D2c, int* __restrict__ D2r,
                                                    int E, int NBIN, int NGR) {
    __shared__ int hc[MAXBIN4], hr[MAXGR4];
    int t = threadIdx.x;
    for (int i = t; i < NBIN; i += 512) hc[i] = 0;
    for (int i = t; i < NGR; i += 512) hr[i] = 0;
    __syncthreads();
    int base = blockIdx.x * SCHUNK;
    int lim = min(SCHUNK, E - base);
    for (int k = t; k < lim; k += 512) {
        int e = base + k;
        atomicAdd(&hc[col[e] >> SH], 1);
        atomicAdd(&hr[row[e] >> SHR4], 1);
    }
    __syncthreads();
    for (int i = t; i < NBIN; i += 512) D2c[(size_t)blockIdx.x * NBIN + i] = hc[i];
    for (int i = t; i < NGR; i += 512) D2r[(size_t)blockIdx.x * NGR + i] = hr[i];
}

// col scatter: counts derived from scanned D2c deltas
__global__ __launch_bounds__(512) void scatter_colS(const int* __restrict__ row,
                                                    const int* __restrict__ col,
                                                    const int* __restrict__ D2c,
                                                    const int* __restrict__ totC,
                                                    const int* __restrict__ basC,
                                                    unsigned int* __restrict__ A1,
                                                    int E, int NBIN, int NBLK) {
    __shared__ unsigned int buf[SCHUNK];        // 64KB
    __shared__ int ls[MAXBIN4];                 // 8KB (starts -> ends)
    __shared__ unsigned short secbin[SCHUNK / 32];  // 1KB
    __shared__ int tmps[512];
    __shared__ int carry;
    int t = threadIdx.x;
    int base = blockIdx.x * SCHUNK;
    int lim = min(SCHUNK, E - base);
    const int* Dg  = D2c + (size_t)blockIdx.x * NBIN;
    const int* Dn  = (blockIdx.x == NBLK - 1) ? totC : Dg + NBIN;
    if (t == 0) carry = 0;
    __syncthreads();
    for (int cb = 0; cb < NBIN; cb += 512) {
        int idx = cb + t;
        int v = (idx < NBIN) ? (Dn[idx] - Dg[idx]) : 0;
        tmps[t] = v;
        __syncthreads();
        for (int d = 1; d < 512; d <<= 1) {
            int u = (t >= d) ? tmps[t - d] : 0;
            __syncthreads();
            tmps[t] += u;
            __syncthreads();
        }
        if (idx < NBIN) ls[idx] = carry + tmps[t] - v;
        __syncthreads();
        if (t == 0) carry += tmps[511];
        __syncthreads();
    }
    for (int k = t; k < lim; k += 512) {
        int e = base + k;
        int c = col[e], r = row[e];
        int bin = c >> SH;
        int p = atomicAdd(&ls[bin], 1);
        buf[p] = (unsigned int)r | ((unsigned int)(c & (BINW - 1)) << 18);
    }
    __syncthreads();
    {
        int pos = t * 32;
        if (pos < lim) {
            int lo = 0, hi = NBIN;
            while (lo < hi) { int mid = (lo + hi) >> 1; if (ls[mid] > pos) hi = mid; else lo = mid + 1; }
            secbin[t] = (unsigned short)lo;
        }
    }
    __syncthreads();
    for (int i = t; i < lim; i += 512) {
        int bin = secbin[i >> 5];
        while (ls[bin] <= i) ++bin;
        int start = (bin > 0) ? ls[bin - 1] : 0;
        A1[Dg[bin] + basC[bin] + (i - start)] = buf[i];
    }
}

// row scatter: counts from D2r deltas
__global__ __launch_bounds__(512) void scatter_rowS(const int* __restrict__ row,
                                                    const int* __restrict__ D2r,
                                                    const int* __restrict__ totR,
                                                    const int* __restrict__ basR,
                                                    unsigned short* __restrict__ B1,
                                                    int E, int NGR, int NBLK) {
    __shared__ unsigned short buf16[SCHUNK];   // 32KB
    __shared__ unsigned char gof[SCHUNK];      // 16KB
    __shared__ int cnt[MAXGR4], ls[MAXGR4], ob[MAXGR4];
    __shared__ int tmps[512];
    int t = threadIdx.x;
    int base = blockIdx.x * SCHUNK;
    int lim = min(SCHUNK, E - base);
    const int* Dg = D2r + (size_t)blockIdx.x * NGR;
    const int* Dn = (blockIdx.x == NBLK - 1) ? totR : Dg + NGR;
    int myv = 0;
    if (t < NGR) {
        int cur = Dg[t];
        myv = Dn[t] - cur;
        ob[t] = cur + basR[t];
        cnt[t] = 0;
    }
    tmps[t] = myv;
    __syncthreads();
    for (int d = 1; d < 512; d <<= 1) {
        int u = (t >= d) ? tmps[t - d] : 0;
        __syncthreads();
        tmps[t] += u;
        __syncthreads();
    }
    if (t < NGR) ls[t] = tmps[t] - myv;
    __syncthreads();
    for (int k = t; k < lim; k += 512) {
        int r = row[base + k];
        int g = r >> SHR4;
        int p = ls[g] + atomicAdd(&cnt[g], 1);
        buf16[p] = (unsigned short)(r & (GWR4 - 1));
        gof[p] = (unsigned char)g;
    }
    __syncthreads();
    for (int i = t; i < lim; i += 512) {
        int g = gof[i];
        B1[ob[g] + (i - ls[g])] = buf16[i];
    }
}

// per row-group out-degree histogram -> dis, fused xs_bf = bf16(dis*x)
__global__ void deg4_kernel(const unsigned short* __restrict__ B1,
                            const int* __restrict__ basR,
                            const float* __restrict__ x,
                            float* __restrict__ dis, uint4* __restrict__ xsb, int N) {
    __shared__ int cnt[GWR4];
    int b = blockIdx.x;
    for (int i = threadIdx.x; i < GWR4; i += blockDim.x) cnt[i] = 0;
    __syncthreads();
    int p0 = basR[b], p1 = basR[b + 1];
    for (int i = p0 + threadIdx.x; i < p1; i += blockDim.x)
        atomicAdd(&cnt[B1[i]], 1);
    __syncthreads();
    for (int i = threadIdx.x; i < GWR4; i += blockDim.x) {
        int node = (b << SHR4) + i;
        if (node < N) {
            int c = cnt[i];
            float d = c > 0 ? rsqrtf((float)c) : 0.f;
            dis[node] = d;
            const float4* xr = reinterpret_cast<const float4*>(x + (size_t)node * 8);
            float4 a = xr[0], bb = xr[1];
            uint4 o;
            o.x = (unsigned int)f2bf(d * a.x) | ((unsigned int)f2bf(d * a.y) << 16);
            o.y = (unsigned int)f2bf(d * a.z) | ((unsigned int)f2bf(d * a.w) << 16);
            o.z = (unsigned int)f2bf(d * bb.x) | ((unsigned int)f2bf(d * bb.y) << 16);
            o.w = (unsigned int)f2bf(d * bb.z) | ((unsigned int)f2bf(d * bb.w) << 16);
            xsb[node] = o;
        }
    }
}

// ======================= fused sort+gather+dense (512-thread, 4 lanes/node) ===========

__global__ __launch_bounds__(512) void gather1S(unsigned int* __restrict__ A1,
                                                const int* __restrict__ basC,
                                                const uint4* __restrict__ xsb,
                                                const float* __restrict__ x,
                                                const float* __restrict__ dis,
                                                const float* __restrict__ W0,
                                                const float* __restrict__ W1,
                                                const float* __restrict__ b1,
                                                const float* __restrict__ W20,
                                                const float* __restrict__ b2,
                                                unsigned int* __restrict__ h1s8,
                                                float* __restrict__ P0,
                                                int* __restrict__ off, int N) {
    __shared__ unsigned int lsrc[GCAP];             // 40KB
    __shared__ int cnt[BINW], fill[BINW], ls[BINW + 1], tmp2[BINW];
    __shared__ float sW0[128], sW1[128], sb1[16], sW20[256], sb2[16];
    int t = threadIdx.x, b = blockIdx.x;
    for (int i = t; i < 128; i += 512) { sW0[i] = W0[i]; sW1[i] = W1[i]; }
    for (int i = t; i < 256; i += 512) sW20[i] = W20[i];
    if (t < 16) { sb1[t] = b1[t]; sb2[t] = b2[t]; }
    if (t < BINW) { cnt[t] = 0; fill[t] = 0; }
    __syncthreads();
    int p0 = basC[b], p1 = basC[b + 1], sz = p1 - p0;

    if (sz <= GCAP) {
        for (int i = t; i < sz; i += 512)
            atomicAdd(&cnt[(A1[p0 + i] >> 18) & (BINW - 1)], 1);
        __syncthreads();
        {
            int v = (t < BINW) ? cnt[t] : 0;
            if (t < BINW) tmp2[t] = v;
            __syncthreads();
            for (int d = 1; d < BINW; d <<= 1) {
                int u = (t >= d && t < BINW) ? tmp2[t - d] : 0;
                __syncthreads();
                if (t < BINW) tmp2[t] += u;
                __syncthreads();
            }
            if (t < BINW) ls[t] = tmp2[t] - v;
            if (t == BINW - 1) ls[BINW] = tmp2[BINW - 1];
        }
        __syncthreads();
        for (int i = t; i < sz; i += 512) {
            unsigned int a = A1[p0 + i];
            int cl = (a >> 18) & (BINW - 1);
            lsrc[ls[cl] + atomicAdd(&fill[cl], 1)] = a;
        }
        __syncthreads();
        for (int i = t; i < sz; i += 512) A1[p0 + i] = lsrc[i];
        if (t < BINW) {
            int node = (b << SH) + t;
            if (node < N) off[node] = p0 + ls[t];
        }
        int n = t >> 2, sub = t & 3;
        int node = (b << SH) + n;
        if (node < N) {
            float tx[8] = {0, 0, 0, 0, 0, 0, 0, 0};
            for (int k = ls[n] + sub; k < ls[n + 1]; k += 4) {
                int r = (int)(lsrc[k] & 0x3FFFFu);
                uint4 q = xsb[r];
                tx[0] += bfLo(q.x); tx[1] += bfHi(q.x);
                tx[2] += bfLo(q.y); tx[3] += bfHi(q.y);
                tx[4] += bfLo(q.z); tx[5] += bfHi(q.z);
                tx[6] += bfLo(q.w); tx[7] += bfHi(q.w);
            }
#pragma unroll
            for (int i = 0; i < 8; ++i) {
                tx[i] += __shfl_xor(tx[i], 1);
                tx[i] += __shfl_xor(tx[i], 2);
            }
            float d = dis[node], sc = -d;
            float xa[8];
            const float4* xr = reinterpret_cast<const float4*>(x + (size_t)node * 8);
            float4 a = xr[0], bb = xr[1];
            xa[0] = a.x; xa[1] = a.y; xa[2] = a.z; xa[3] = a.w;
            xa[4] = bb.x; xa[5] = bb.y; xa[6] = bb.z; xa[7] = bb.w;
            int ob = sub * 4;
            float acc[4];
#pragma unroll
            for (int j = 0; j < 4; ++j) acc[j] = sb1[ob + j];
#pragma unroll
            for (int f = 0; f < 8; ++f) {
                float xv = xa[f], tv = sc * tx[f];
#pragma unroll
                for (int j = 0; j < 4; ++j)
                    acc[j] += xv * sW0[f * 16 + ob + j] + tv * sW1[f * 16 + ob + j];
            }
            float h[4];
#pragma unroll
            for (int j = 0; j < 4; ++j) h[j] = fmaxf(acc[j], 0.f);
            float ds = d * FP8S;
            h1s8[(size_t)node * 4 + sub] = pk4_fp8(ds * h[0], ds * h[1], ds * h[2], ds * h[3]);
            float hall[16];
#pragma unroll
            for (int src = 0; src < 4; ++src) {
#pragma unroll
                for (int j = 0; j < 4; ++j) hall[src * 4 + j] = __shfl(h[j], src, 4);
            }
            float pp[4];
#pragma unroll
            for (int j = 0; j < 4; ++j) pp[j] = sb2[ob + j];
#pragma unroll
            for (int f = 0; f < 16; ++f) {
                float hv = hall[f];
#pragma unroll
                for (int j = 0; j < 4; ++j) pp[j] += hv * sW20[f * 16 + ob + j];
            }
            reinterpret_cast<float4*>(P0 + (size_t)node * 16)[sub] =
                make_float4(pp[0], pp[1], pp[2], pp[3]);
        }
    } else {
        // oversized bin (not expected): LDS f32-atomic accumulation; still writes off[]
        float* txf = (float*)lsrc;   // [BINW][9]
        for (int i = t; i < BINW * 9; i += 512) txf[i] = 0.f;
        __syncthreads();
        for (int i = t; i < sz; i += 512) {
            unsigned int a = A1[p0 + i];
            int r = a & 0x3FFFF, cl = (a >> 18) & (BINW - 1);
            atomicAdd(&cnt[cl], 1);
            uint4 q = xsb[r];
            atomicAdd(&txf[cl * 9 + 0], bfLo(q.x)); atomicAdd(&txf[cl * 9 + 1], bfHi(q.x));
            atomicAdd(&txf[cl * 9 + 2], bfLo(q.y)); atomicAdd(&txf[cl * 9 + 3], bfHi(q.y));
            atomicAdd(&txf[cl * 9 + 4], bfLo(q.z)); atomicAdd(&txf[cl * 9 + 5], bfHi(q.z));
            atomicAdd(&txf[cl * 9 + 6], bfLo(q.w)); atomicAdd(&txf[cl * 9 + 7], bfHi(q.w));
        }
        __syncthreads();
        if (t == 0) { int a = 0; for (int i = 0; i < BINW; ++i) { ls[i] = a; a += cnt[i]; } }
        __syncthreads();
        if (t < BINW) {
            int node = (b << SH) + t;
            if (node < N) {
                off[node] = p0 + ls[t];
                float d = dis[node], sc = -d;
                float xa[8];
                const float4* xr = reinterpret_cast<const float4*>(x + (size_t)node * 8);
                float4 a = xr[0], bb = xr[1];
                xa[0] = a.x; xa[1] = a.y; xa[2] = a.z; xa[3] = a.w;
                xa[4] = bb.x; xa[5] = bb.y; xa[6] = bb.z; xa[7] = bb.w;
                float acc[16];
#pragma unroll
                for (int o = 0; o < 16; ++o) acc[o] = sb1[o];
#pragma unroll
                for (int f = 0; f < 8; ++f) {
                    float xv = xa[f], tv = sc * txf[t * 9 + f];
#pragma unroll
                    for (int o = 0; o < 16; ++o)
                        acc[o] += xv * sW0[f * 16 + o] + tv * sW1[f * 16 + o];
                }
                float h[16];
#pragma unroll
                for (int o = 0; o < 16; ++o) h[o] = fmaxf(acc[o], 0.f);
                float ds = d * FP8S;
#pragma unroll
                for (int v = 0; v < 4; ++v)
                    h1s8[(size_t)node * 4 + v] = pk4_fp8(ds * h[v * 4 + 0], ds * h[v * 4 + 1],
                                                         ds * h[v * 4 + 2], ds * h[v * 4 + 3]);
                float pp[16];
#pragma unroll
                for (int o = 0; o < 16; ++o) pp[o] = sb2[o];
#pragma unroll
                for (int f = 0; f < 16; ++f) {
                    float hv = h[f];
#pragma unroll
                    for (int o = 0; o < 16; ++o) pp[o] += hv * sW20[f * 16 + o];
                }
                float4* po = reinterpret_cast<float4*>(P0 + (size_t)node * 16);
#pragma unroll
                for (int v = 0; v < 4; ++v)
                    po[v] = make_float4(pp[v * 4], pp[v * 4 + 1], pp[v * 4 + 2], pp[v * 4 + 3]);
            }
        }
    }
}

__global__ __launch_bounds__(512) void gather2S(const unsigned int* __restrict__ A1,
                                                const int* __restrict__ basC,
                                                const int* __restrict__ off,
                                                const uint4* __restrict__ h1s8,
                                                const float* __restrict__ P0,
                                                const float* __restrict__ dis,
                                                const float* __restrict__ W21,
                                                const float* __restrict__ Wr,
                                                const float* __restrict__ br,
                                                float* __restrict__ s, int N) {
    __shared__ unsigned int lsrc[GCAP];
    __shared__ float sW1[256], sWr[16], sbr;
    int t = threadIdx.x, b = blockIdx.x;
    for (int i = t; i < 256; i += 512) sW1[i] = W21[i];
    if (t < 16) sWr[t] = Wr[t];
    if (t == 0) sbr = br[0];
    __syncthreads();
    int p0 = basC[b], p1 = basC[b + 1], sz = p1 - p0;

    if (sz <= GCAP) {
        for (int i = t; i < sz; i += 512) lsrc[i] = __builtin_nontemporal_load(&A1[p0 + i]);
        __syncthreads();
        int n = t >> 2, sub = t & 3;
        int node = (b << SH) + n;
        if (node < N) {
            int st = off[node] - p0;
            int en = (n == BINW - 1 || node == N - 1) ? sz : off[node + 1] - p0;
            float tx[16];
#pragma unroll
            for (int o = 0; o < 16; ++o) tx[o] = 0.f;
            for (int k = st + sub; k < en; k += 4) {
                int r = (int)(lsrc[k] & 0x3FFFFu);
                uint4 q = h1s8[r];
                v2f p;
                p = __builtin_amdgcn_cvt_pk_f32_fp8((int)q.x, false); tx[0]  += p.x; tx[1]  += p.y;
                p = __builtin_amdgcn_cvt_pk_f32_fp8((int)q.x, true);  tx[2]  += p.x; tx[3]  += p.y;
                p = __builtin_amdgcn_cvt_pk_f32_fp8((int)q.y, false); tx[4]  += p.x; tx[5]  += p.y;
                p = __builtin_amdgcn_cvt_pk_f32_fp8((int)q.y, true);  tx[6]  += p.x; tx[7]  += p.y;
                p = __builtin_amdgcn_cvt_pk_f32_fp8((int)q.z, false); tx[8]  += p.x; tx[9]  += p.y;
                p = __builtin_amdgcn_cvt_pk_f32_fp8((int)q.z, true);  tx[10] += p.x; tx[11] += p.y;
                p = __builtin_amdgcn_cvt_pk_f32_fp8((int)q.w, false); tx[12] += p.x; tx[13] += p.y;
                p = __builtin_amdgcn_cvt_pk_f32_fp8((int)q.w, true);  tx[14] += p.x; tx[15] += p.y;
            }
#pragma unroll
            for (int i = 0; i < 16; ++i) {
                tx[i] += __shfl_xor(tx[i], 1);
                tx[i] += __shfl_xor(tx[i], 2);
            }
            float sc = -dis[node] * FP8SI;
            int ob = sub * 4;
            float4 pq = reinterpret_cast<const float4*>(P0 + (size_t)node * 16)[sub];
            float acc[4] = {pq.x, pq.y, pq.z, pq.w};
#pragma unroll
            for (int f = 0; f < 16; ++f) {
                float tv = sc * tx[f];
#pragma unroll
                for (int j = 0; j < 4; ++j) acc[j] += tv * sW1[f * 16 + ob + j];
            }
            float sv = 0.f;
#pragma unroll
            for (int j = 0; j < 4; ++j) sv += fmaxf(acc[j], 0.f) * sWr[ob + j];
            sv += __shfl_xor(sv, 1);
            sv += __shfl_xor(sv, 2);
            if (sub == 0) s[node] = sv + sbr;
        }
    } else {
        float* txf = (float*)lsrc;   // [BINW][17]
        for (int i = t; i < BINW * 17; i += 512) txf[i] = 0.f;
        __syncthreads();
        for (int i = t; i < sz; i += 512) {
            unsigned int a = A1[p0 + i];
            int r = a & 0x3FFFF, cl = (a >> 18) & (BINW - 1);
            uint4 q = h1s8[r];
            v2f p;
            p = __builtin_amdgcn_cvt_pk_f32_fp8((int)q.x, false);
            atomicAdd(&txf[cl * 17 + 0], p.x);  atomicAdd(&txf[cl * 17 + 1], p.y);
            p = __builtin_amdgcn_cvt_pk_f32_fp8((int)q.x, true);
            atomicAdd(&txf[cl * 17 + 2], p.x);  atomicAdd(&txf[cl * 17 + 3], p.y);
            p = __builtin_amdgcn_cvt_pk_f32_fp8((int)q.y, false);
            atomicAdd(&txf[cl * 17 + 4], p.x);  atomicAdd(&txf[cl * 17 + 5], p.y);
            p = __builtin_amdgcn_cvt_pk_f32_fp8((int)q.y, true);
            atomicAdd(&txf[cl * 17 + 6], p.x);  atomicAdd(&txf[cl * 17 + 7], p.y);
            p = __builtin_amdgcn_cvt_pk_f32_fp8((int)q.z, false);
            atomicAdd(&txf[cl * 17 + 8], p.x);  atomicAdd(&txf[cl * 17 + 9], p.y);
            p = __builtin_amdgcn_cvt_pk_f32_fp8((int)q.z, true);
            atomicAdd(&txf[cl * 17 + 10], p.x); atomicAdd(&txf[cl * 17 + 11], p.y);
            p = __builtin_amdgcn_cvt_pk_f32_fp8((int)q.w, false);
            atomicAdd(&txf[cl * 17 + 12], p.x); atomicAdd(&txf[cl * 17 + 13], p.y);
            p = __builtin_amdgcn_cvt_pk_f32_fp8((int)q.w, true);
            atomicAdd(&txf[cl * 17 + 14], p.x); atomicAdd(&txf[cl * 17 + 15], p.y);
        }
        __syncthreads();
        if (t < BINW) {
            int node = (b << SH) + t;
            if (node < N) {
                float sc = -dis[node] * FP8SI;
                float acc[16];
                const float4* pr = reinterpret_cast<const float4*>(P0 + (size_t)node * 16);
#pragma unroll
                for (int v = 0; v < 4; ++v) {
                    float4 q = pr[v];
                    acc[v * 4 + 0] = q.x; acc[v * 4 + 1] = q.y;
                    acc[v * 4 + 2] = q.z; acc[v * 4 + 3] = q.w;
                }
#pragma unroll
                for (int f = 0; f < 16; ++f) {
                    float tv = sc * txf[t * 17 + f];
#pragma unroll
                    for (int o = 0; o < 16; ++o) acc[o] += tv * sW1[f * 16 + o];
                }
                float sv = sbr;
#pragma unroll
                for (int o = 0; o < 16; ++o) sv += fmaxf(acc[o], 0.f) * sWr[o];
                s[node] = sv;
            }
        }
    }
}

__global__ void softmax_kernel(const float* __restrict__ s, const int* __restrict__ batch,
                               float* __restrict__ out, int N) {
    int g = blockIdx.x;
    __shared__ float red[THREADS];
    int lo, hi;
    { int a = 0, b = N; while (a < b) { int mid = (a + b) >> 1; if (batch[mid] < g) a = mid + 1; else b = mid; } lo = a; }
    { int a = lo, b = N; while (a < b) { int mid = (a + b) >> 1; if (batch[mid] < g + 1) a = mid + 1; else b = mid; } hi = a; }
    float mx = -INFINITY;
    for (int i = lo + threadIdx.x; i < hi; i += THREADS) mx = fmaxf(mx, s[i]);
    red[threadIdx.x] = mx;
    __syncthreads();
    for (int d = THREADS / 2; d > 0; d >>= 1) {
        if (threadIdx.x < d) red[threadIdx.x] = fmaxf(red[threadIdx.x], red[threadIdx.x + d]);
        __syncthreads();
    }
    mx = red[0];
    __syncthreads();
    float sum = 0.f;
    for (int i = lo + threadIdx.x; i < hi; i += THREADS) sum += expf(s[i] - mx);
    red[threadIdx.x] = sum;
    __syncthreads();
    for (int d = THREADS / 2; d > 0; d >>= 1) {
        if (threadIdx.x < d) red[threadIdx.x] += red[threadIdx.x + d];
        __syncthreads();
    }
    float inv = 1.f / red[0];
    for (int i = lo + threadIdx.x; i < hi; i += THREADS) out[i] = expf(s[i] - mx) * inv;
}

// ======================= generic fallback (round-2 CSR + w4 gathers, fp32) =======================

__global__ void deg_cnt_kernel(const int* __restrict__ row, const int* __restrict__ col,
                               int* __restrict__ deg_i, int* __restrict__ cnt, int E) {
    int e = blockIdx.x * blockDim.x + threadIdx.x;
    if (e >= E) return;
    atomicAdd(&deg_i[row[e]], 1);
    atomicAdd(&cnt[col[e]], 1);
}

__global__ void dis_kernel_i(const int* __restrict__ deg_i, float* __restrict__ dis, int N) {
    int i = blockIdx.x * blockDim.x + threadIdx.x;
    if (i < N) {
        int d = deg_i[i];
        dis[i] = d > 0 ? rsqrtf((float)d) : 0.f;
    }
}

__global__ void scan1_kernel(const int* __restrict__ cnt, int* __restrict__ off,
                             int* __restrict__ bsum, int n) {
    __shared__ int tmp[THREADS];
    int i = blockIdx.x * THREADS + threadIdx.x;
    int v = (i < n) ? cnt[i] : 0;
    tmp[threadIdx.x] = v;
    __syncthreads();
    for (int d = 1; d < THREADS; d <<= 1) {
        int t = (threadIdx.x >= d) ? tmp[threadIdx.x - d] : 0;
        __syncthreads();
        tmp[threadIdx.x] += t;
        __syncthreads();
    }
    if (i < n) off[i] = tmp[threadIdx.x] - v;
    if (threadIdx.x == THREADS - 1) bsum[blockIdx.x] = tmp[threadIdx.x];
}

__global__ void scan2_kernel(int* __restrict__ bsum, int nb) {
    __shared__ int tmp[1024];
    int carry = 0;
    for (int base = 0; base < nb; base += 1024) {
        int i = base + threadIdx.x;
        int v = (i < nb) ? bsum[i] : 0;
        tmp[threadIdx.x] = v;
        __syncthreads();
        for (int d = 1; d < 1024; d <<= 1) {
            int t = (threadIdx.x >= d) ? tmp[threadIdx.x - d] : 0;
            __syncthreads();
            tmp[threadIdx.x] += t;
            __syncthreads();
        }
        if (i < nb) bsum[i] = carry + tmp[threadIdx.x] - v;
        carry += tmp[1023];
        __syncthreads();
    }
}

__global__ void scan3_kernel(int* __restrict__ off, const int* __restrict__ bsum, int n) {
    int i = blockIdx.x * THREADS + threadIdx.x;
    if (i < n) off[i] += bsum[blockIdx.x];
}

__global__ void fill_csr_kernel(const int* __restrict__ row, const int* __restrict__ col,
                                const int* __restrict__ off, int* __restrict__ fill,
                                int* __restrict__ csr_src, int E) {
    int e = blockIdx.x * blockDim.x + threadIdx.x;
    if (e >= E) return;
    int c = col[e];
    int p = off[c] + atomicAdd(&fill[c], 1);
    csr_src[p] = row[e];
}

__global__ void gather_dense1_w4(const int* __restrict__ off, const int* __restrict__ csr_src,
                                 const float* __restrict__ dis, const float* __restrict__ x,
                                 const float* __restrict__ W0, const float* __restrict__ W1,
                                 const float* __restrict__ b, float* __restrict__ h1,
                                 int N, int E) {
    __shared__ float sW0[128], sW1[128], sb[16];
    for (int i = threadIdx.x; i < 128; i += blockDim.x) { sW0[i] = W0[i]; sW1[i] = W1[i]; }
    if (threadIdx.x < 16) sb[threadIdx.x] = b[threadIdx.x];
    __syncthreads();
    int t = blockIdx.x * blockDim.x + threadIdx.x;
    int g = t >> 2, sub = t & 3;
    if (g >= N) return;
    int p0 = off[g], p1 = (g == N - 1) ? E : off[g + 1];
    float tx[8] = {0, 0, 0, 0, 0, 0, 0, 0};
    for (int p = p0 + sub; p < p1; p += 4) {
        int src = csr_src[p];
        float wv = dis[src];
        const float4* fr = reinterpret_cast<const float4*>(x + (size_t)src * 8);
        float4 a = fr[0], bb = fr[1];
        tx[0] += wv * a.x;  tx[1] += wv * a.y;  tx[2] += wv * a.z;  tx[3] += wv * a.w;
        tx[4] += wv * bb.x; tx[5] += wv * bb.y; tx[6] += wv * bb.z; tx[7] += wv * bb.w;
    }
#pragma unroll
    for (int i = 0; i < 8; ++i) {
        tx[i] += __shfl_xor(tx[i], 1);
        tx[i] += __shfl_xor(tx[i], 2);
    }
    float xa[8];
    const float4* xr = reinterpret_cast<const float4*>(x + (size_t)g * 8);
    float4 a = xr[0], bb = xr[1];
    xa[0] = a.x; xa[1] = a.y; xa[2] = a.z; xa[3] = a.w;
    xa[4] = bb.x; xa[5] = bb.y; xa[6] = bb.z; xa[7] = bb.w;
    float sc = -dis[g];
    int ob = sub * 4;
    float acc[4];
#pragma unroll
    for (int j = 0; j < 4; ++j) acc[j] = sb[ob + j];
#pragma unroll
    for (int f = 0; f < 8; ++f) {
        float xv = xa[f], tv = sc * tx[f];
#pragma unroll
        for (int j = 0; j < 4; ++j) acc[j] += xv * sW0[f * 16 + ob + j] + tv * sW1[f * 16 + ob + j];
    }
    float4 q;
    q.x = fmaxf(acc[0], 0.f); q.y = fmaxf(acc[1], 0.f);
    q.z = fmaxf(acc[2], 0.f); q.w = fmaxf(acc[3], 0.f);
    reinterpret_cast<float4*>(h1 + (size_t)g * 16)[sub] = q;
}

__global__ void gather_dense2_w4(const int* __restrict__ off, const int* __restrict__ csr_src,
                                 const float* __restrict__ dis, const float* __restrict__ h1,
                                 const float* __restrict__ W0, const float* __restrict__ W1,
                                 const float* __restrict__ b, const float* __restrict__ Wr,
                                 const float* __restrict__ br, float* __restrict__ s,
                                 int N, int E) {
    __shared__ float sW0[256], sW1[256], sb[16], sWr[16], sbr;
    for (int i = threadIdx.x; i < 256; i += blockDim.x) { sW0[i] = W0[i]; sW1[i] = W1[i]; }
    if (threadIdx.x < 16) { sb[threadIdx.x] = b[threadIdx.x]; sWr[threadIdx.x] = Wr[threadIdx.x]; }
    if (threadIdx.x == 0) sbr = br[0];
    __syncthreads();
    int t = blockIdx.x * blockDim.x + threadIdx.x;
    int g = t >> 2, sub = t & 3;
    if (g >= N) return;
    int p0 = off[g], p1 = (g == N - 1) ? E : off[g + 1];
    float tx[16];
#pragma unroll
    for (int o = 0; o < 16; ++o) tx[o] = 0.f;
    for (int p = p0 + sub; p < p1; p += 4) {
        int src = csr_src[p];
        float wv = dis[src];
        const float4* fr = reinterpret_cast<const float4*>(h1 + (size_t)src * 16);
#pragma unroll
        for (int v = 0; v < 4; ++v) {
            float4 q = fr[v];
            tx[v * 4 + 0] += wv * q.x;
            tx[v * 4 + 1] += wv * q.y;
            tx[v * 4 + 2] += wv * q.z;
            tx[v * 4 + 3] += wv * q.w;
        }
    }
#pragma unroll
    for (int i = 0; i < 16; ++i) {
        tx[i] += __shfl_xor(tx[i], 1);
        tx[i] += __shfl_xor(tx[i], 2);
    }
    float ha[16];
    const float4* hr = reinterpret_cast<const float4*>(h1 + (size_t)g * 16);
#pragma unroll
    for (int v = 0; v < 4; ++v) {
        float4 q = hr[v];
        ha[v * 4 + 0] = q.x; ha[v * 4 + 1] = q.y; ha[v * 4 + 2] = q.z; ha[v * 4 + 3] = q.w;
    }
    float sc = -dis[g];
    int ob = sub * 4;
    float acc[4];
#pragma unroll
    for (int j = 0; j < 4; ++j) acc[j] = sb[ob + j];
#pragma unroll
    for (int f = 0; f < 16; ++f) {
        float hv = ha[f], tv = sc * tx[f];
#pragma unroll
        for (int j = 0; j < 4; ++j) acc[j] += hv * sW0[f * 16 + ob + j] + tv * sW1[f * 16 + ob + j];
    }
    float sv = 0.f;
#pragma unroll
    for (int j = 0; j < 4; ++j) sv += fmaxf(acc[j], 0.f) * sWr[ob + j];
    sv += __shfl_xor(sv, 1);
    sv += __shfl_xor(sv, 2);
    if (sub == 0) s[g] = sv + sbr;
}

// ======================= launch =======================

extern "C" void kernel_launch(void* const* d_in, const int* in_sizes, int n_in,
                              void* d_out, int out_size, void* d_ws, size_t ws_size,
                              hipStream_t stream) {
    const float* x     = (const float*)d_in[0];
    const int*   ei    = (const int*)d_in[1];
    const int*   batch = (const int*)d_in[2];
    const float* W1_0  = (const float*)d_in[3];
    const float* W1_1  = (const float*)d_in[4];
    const float* b1    = (const float*)d_in[5];
    const float* W2_0  = (const float*)d_in[6];
    const float* W2_1  = (const float*)d_in[7];
    const float* b2    = (const float*)d_in[8];
    const float* Wr    = (const float*)d_in[9];
    const float* br    = (const float*)d_in[10];
    float* out = (float*)d_out;

    const int N = in_sizes[2];
    const int E = in_sizes[1] / 2;
    const int G = 256;
    const int* row = ei;
    const int* col = ei + E;

    const int gN = (N + THREADS - 1) / THREADS;
    const int gE = (E + THREADS - 1) / THREADS;
    const int gW = ((size_t)N * 4 + THREADS - 1) / THREADS;

    auto al = [](size_t v) { return (v + 255) & ~(size_t)255; };
    auto maxz = [](size_t a, size_t b) { return a > b ? a : b; };

    // -------- layout --------
    const int NBIN  = (N + BINW - 1) >> SH;
    const int NGR   = (N + GWR4 - 1) >> SHR4;
    const int NBLK4 = (E + SCHUNK - 1) / SCHUNK;
    size_t rA1  = al((size_t)E * 4);
    size_t rB1H = al(maxz((size_t)E * 2, (size_t)80 * N));  // B1 ∪ h1s8(16B/n)+P0(64B/n)
    size_t rDIS = al((size_t)N * 4);
    size_t rS   = al((size_t)N * 4);
    size_t rXS  = al((size_t)16 * N);       // bf16 xs
    size_t rOFF = al((size_t)N * 4);
    size_t nHist = (size_t)NBLK4 * NBIN + NBIN + (NBIN + 1) +
                   (size_t)NBLK4 * NGR + NGR + (NGR + 1);
    size_t rHIST = al(nHist * 4);
    size_t need_v9 = rA1 + rB1H + rDIS + rS + rXS + rOFF + rHIST;

    if (N <= (1 << 18) && NBIN <= MAXBIN4 && NGR <= MAXGR4 && ws_size >= need_v9) {
        char* base = (char*)d_ws;
        unsigned int* A1   = (unsigned int*)base;
        unsigned short* B1 = (unsigned short*)(base + rA1);
        unsigned int* h1s8 = (unsigned int*)(base + rA1);    // after deg4 (16B/node)
        float* P0   = (float*)(base + rA1 + (size_t)16 * N);
        float* dis = (float*)(base + rA1 + rB1H);
        float* s   = (float*)(base + rA1 + rB1H + rDIS);
        uint4* xsb = (uint4*)(base + rA1 + rB1H + rDIS + rS);
        int* off   = (int*)(base + rA1 + rB1H + rDIS + rS + rXS);
        int* hist  = (int*)(base + rA1 + rB1H + rDIS + rS + rXS + rOFF);
        int* D2c  = hist;
        int* totC = D2c + (size_t)NBLK4 * NBIN;
        int* basC = totC + NBIN;
        int* D2r  = basC + NBIN + 1;
        int* totR = D2r + (size_t)NBLK4 * NGR;
        int* basR = totR + NGR;

        hist4_kernel<<<NBLK4, 512, 0, stream>>>(row, col, D2c, D2r, E, NBIN, NGR);
        scan_col2_kernel<<<NBIN + NGR, THREADS, 0, stream>>>(D2c, totC, NBIN, D2r, totR, NGR, NBLK4);
        scan_bins2_kernel<<<2, 1024, 0, stream>>>(totC, basC, NBIN, totR, basR, NGR);
        scatter_colS<<<NBLK4, 512, 0, stream>>>(row, col, D2c, totC, basC, A1, E, NBIN, NBLK4);
        scatter_rowS<<<NBLK4, 512, 0, stream>>>(row, D2r, totR, basR, B1, E, NGR, NBLK4);
        deg4_kernel<<<NGR, 1024, 0, stream>>>(B1, basR, x, dis, xsb, N);  // B1 dead after
        gather1S<<<NBIN, 512, 0, stream>>>(A1, basC, xsb, x, dis, W1_0, W1_1, b1,
                                           W2_0, b2, h1s8, P0, off, N);
        gather2S<<<NBIN, 512, 0, stream>>>(A1, basC, off, (const uint4*)h1s8, P0, dis,
                                           W2_1, Wr, br, s, N);
        softmax_kernel<<<G, THREADS, 0, stream>>>(s, batch, out, N);
    } else {
        // generic fallback: atomic CSR build + w4 gathers (fp32)
        int* deg_i = (int*)d_ws;
        int* cnt   = deg_i + N;
        int* fill  = cnt + N;
        int* off   = fill + N;
        int* bsum  = off + N;
        float* dis = (float*)(bsum + 1024);
        float* h1  = dis + N;
        float* s   = h1 + (size_t)16 * N;
        int* csr   = (int*)(s + N);

        hipMemsetAsync(deg_i, 0, sizeof(int) * (size_t)3 * N, stream);

        deg_cnt_kernel<<<gE, THREADS, 0, stream>>>(row, col, deg_i, cnt, E);
        dis_kernel_i<<<gN, THREADS, 0, stream>>>(deg_i, dis, N);
        scan1_kernel<<<gN, THREADS, 0, stream>>>(cnt, off, bsum, N);
        scan2_kernel<<<1, 1024, 0, stream>>>(bsum, gN);
        scan3_kernel<<<gN, THREADS, 0, stream>>>(off, bsum, N);
        fill_csr_kernel<<<gE, THREADS, 0, stream>>>(row, col, off, fill, csr, E);
        gather_dense1_w4<<<gW, THREADS, 0, stream>>>(off, csr, dis, x, W1_0, W1_1, b1, h1, N, E);
        gather_dense2_w4<<<gW, THREADS, 0, stream>>>(off, csr, dis, h1, W2_0, W2_1, b2, Wr, br, s, N, E);
        softmax_kernel<<<G, THREADS, 0, stream>>>(s, batch, out, N);
    }
}